// Round 21
// baseline (369.525 us; speedup 1.0000x reference)
//
#include <hip/hip_runtime.h>
#include <hip/hip_bf16.h>
#include <math.h>

#define GG 2048          // conv0 grid
#define NB_SHIFT 9       // 512 nodes per bin
#define NPB 512
#define BINCAP 10240     // edges per bin (mean 8192, 6-sigma ~8740)
#define BINREGION 12288  // padded words per bin bucket region
#define PCHUNK 2048      // edges per partition chunk
#define CSB 64           // colsumW blocks (ticket fence cheap at 64, R20-validated)

typedef __hip_bfloat16 bf16;
typedef unsigned int uint;
typedef unsigned short ushort;
typedef unsigned char uchar;
typedef short bf16x8 __attribute__((ext_vector_type(8)));
typedef float f32x4 __attribute__((ext_vector_type(4)));
typedef float f32x2 __attribute__((ext_vector_type(2)));

__device__ __forceinline__ bf16  f2b(float x) { return __float2bfloat16(x); }
__device__ __forceinline__ short f2bs(float x) {
    bf16 b = __float2bfloat16(x);
    return *reinterpret_cast<short*>(&b);
}
// fp8 e4m3-packed pos/neg: byte0=pos, byte1=neg per dim
__device__ __forceinline__ ushort packfp8(float p, float n) {
    return (ushort)__builtin_amdgcn_cvt_pk_fp8_f32(p, n, 0, false);
}
__device__ __forceinline__ f32x2 unpackfp8(uint u) {
    return __builtin_amdgcn_cvt_pk_f32_fp8((int)u, false);
}
__device__ __forceinline__ f32x2 unpackfp8_hi(uint u) {
    return __builtin_amdgcn_cvt_pk_f32_fp8((int)u, true);
}

// ---- zero: w[N], bincnt, lossacc, flag ------------------------------------
__global__ __launch_bounds__(256) void zero_kernel(
        float* __restrict__ w, int* __restrict__ bincnt,
        float* __restrict__ lossacc, int* __restrict__ flags, int nb, int n) {
    int tid = blockIdx.x * 256 + threadIdx.x;
    for (int i = tid; i < n; i += gridDim.x * 256) w[i] = 0.f;
    if (tid < nb) bincnt[tid] = 0;
    if (tid < 2) { lossacc[tid] = 0.f; flags[tid] = 0; }
}

// ---- P1: partition edges into bins of 512 nodes; u = (r<<9)|(c&511) -------
__global__ __launch_bounds__(256) void partition_edges(
        const int* __restrict__ row, const int* __restrict__ col,
        uint* __restrict__ bins, int* __restrict__ bincnt, int E, int nb) {
    __shared__ int lcnt[256];
    __shared__ int lbase[256];
    for (int chunk = blockIdx.x * PCHUNK; chunk < E; chunk += gridDim.x * PCHUNK) {
        int end = chunk + PCHUNK < E ? chunk + PCHUNK : E;
        if (threadIdx.x < nb) lcnt[threadIdx.x] = 0;
        __syncthreads();
        for (int e = chunk + threadIdx.x; e < end; e += 256)
            atomicAdd(&lcnt[col[e] >> NB_SHIFT], 1);
        __syncthreads();
        if (threadIdx.x < nb) {
            lbase[threadIdx.x] = atomicAdd(&bincnt[threadIdx.x], lcnt[threadIdx.x]);
            lcnt[threadIdx.x] = 0;
        }
        __syncthreads();
        for (int e = chunk + threadIdx.x; e < end; e += 256) {
            int c = col[e], r = row[e];
            int g = c >> NB_SHIFT;
            int dst = lbase[g] + atomicAdd(&lcnt[g], 1);
            if (dst < BINCAP)
                bins[(size_t)g * BINCAP + dst] = ((uint)r << NB_SHIFT) | (uint)(c & (NPB - 1));
        }
        __syncthreads();
    }
}

// ---- P2: per bin: LDS hist -> cnt; padded scan -> off; LDS scatter;
// coalesced write-out. Also scatters w[r] += dis[c] (layer-2 colsum weights).
__global__ __launch_bounds__(256) void place_lds(
        const uint* __restrict__ bins, const int* __restrict__ bincnt,
        int* __restrict__ bucket, int* __restrict__ off, int* __restrict__ cnt,
        float* __restrict__ w, int N) {
    __shared__ int lcnt[NPB];
    __shared__ int s[NPB];
    __shared__ int win[BINREGION];
    int b  = blockIdx.x;
    int lo = b << NB_SHIFT;
    int base = b * BINREGION;
    int ne = bincnt[b];
    if (ne > BINCAP) ne = BINCAP;
    const uint* be = bins + (size_t)b * BINCAP;
    for (int i = threadIdx.x; i < NPB; i += 256) lcnt[i] = 0;
    __syncthreads();
    for (int i = threadIdx.x; i < ne; i += 256)
        atomicAdd(&lcnt[be[i] & (NPB - 1)], 1);
    __syncthreads();
    // w scatter: w[row] += rsqrt(deg(col)+1)  (lcnt still holds counts here)
    for (int i = threadIdx.x; i < ne; i += 256) {
        uint u = be[i];
        atomicAdd(&w[(int)(u >> NB_SHIFT)],
                  rsqrtf((float)lcnt[u & (NPB - 1)] + 1.0f));
    }
    int i0 = threadIdx.x, i1 = threadIdx.x + 256;
    s[i0] = (lcnt[i0] + 3) & ~3;
    s[i1] = (lcnt[i1] + 3) & ~3;
    __syncthreads();
    for (int st = 1; st < NPB; st <<= 1) {
        int v0 = i0 >= st ? s[i0 - st] : 0;
        int v1 = i1 >= st ? s[i1 - st] : 0;
        __syncthreads();
        s[i0] += v0; s[i1] += v1;
        __syncthreads();
    }
    for (int i = threadIdx.x; i < NPB; i += 256) {
        int v = lo + i;
        int pc = (lcnt[i] + 3) & ~3;
        int start = s[i] - pc;
        if (v < N) { off[v] = base + start; cnt[v] = lcnt[i]; }
        lcnt[i] = start;
    }
    __syncthreads();
    for (int i = threadIdx.x; i < ne; i += 256) {
        uint u = be[i];
        int slot = atomicAdd(&lcnt[u & (NPB - 1)], 1);
        if (slot < BINREGION) win[slot] = (int)(u >> NB_SHIFT);
    }
    __syncthreads();
    int wsize = s[NPB - 1];
    if (wsize > BINREGION) wsize = BINREGION;
    for (int i = threadIdx.x * 4; i < wsize; i += 1024)
        *(int4*)&bucket[base + i] = *(const int4*)&win[i];
}

// ---- layer-1 GEMM via MFMA; fp8-packed output -----------------------------
__global__ __launch_bounds__(256) void gemm1_mfma(
        const float* __restrict__ X, const float* __restrict__ W,
        const int* __restrict__ perm, const int* __restrict__ cnt,
        ushort* __restrict__ out, int n) {
    int lane = threadIdx.x & 63, wid = threadIdx.x >> 6;
    int l15 = lane & 15, lg = lane >> 4;
    bf16x8 bfr[2][4];
#pragma unroll
    for (int kt = 0; kt < 2; kt++)
#pragma unroll
        for (int nt = 0; nt < 4; nt++)
#pragma unroll
            for (int i = 0; i < 8; i++)
                bfr[kt][nt][i] = f2bs(W[(kt * 32 + lg * 8 + i) * 64 + nt * 16 + l15]);
    int ntiles = (n + 15) >> 4;
    for (int t = blockIdx.x * 4 + wid; t < ntiles; t += gridDim.x * 4) {
        int rowA = t * 16 + l15;
        if (rowA >= n) rowA = n - 1;
        int prow = perm[rowA];
        const float4* xp = (const float4*)(X + (size_t)rowA * 64);
        const float4* xn = (const float4*)(X + (size_t)prow * 64);
        bf16x8 ap[2], an[2];
#pragma unroll
        for (int kt = 0; kt < 2; kt++) {
            float4 p0 = xp[kt * 8 + lg * 2], p1 = xp[kt * 8 + lg * 2 + 1];
            float4 n0 = xn[kt * 8 + lg * 2], n1 = xn[kt * 8 + lg * 2 + 1];
            ap[kt][0] = f2bs(p0.x); ap[kt][1] = f2bs(p0.y);
            ap[kt][2] = f2bs(p0.z); ap[kt][3] = f2bs(p0.w);
            ap[kt][4] = f2bs(p1.x); ap[kt][5] = f2bs(p1.y);
            ap[kt][6] = f2bs(p1.z); ap[kt][7] = f2bs(p1.w);
            an[kt][0] = f2bs(n0.x); an[kt][1] = f2bs(n0.y);
            an[kt][2] = f2bs(n0.z); an[kt][3] = f2bs(n0.w);
            an[kt][4] = f2bs(n1.x); an[kt][5] = f2bs(n1.y);
            an[kt][6] = f2bs(n1.z); an[kt][7] = f2bs(n1.w);
        }
        f32x4 accp[4], accn[4];
#pragma unroll
        for (int nt = 0; nt < 4; nt++) { accp[nt] = (f32x4)0.f; accn[nt] = (f32x4)0.f; }
#pragma unroll
        for (int nt = 0; nt < 4; nt++) {
            accp[nt] = __builtin_amdgcn_mfma_f32_16x16x32_bf16(ap[0], bfr[0][nt], accp[nt], 0, 0, 0);
            accp[nt] = __builtin_amdgcn_mfma_f32_16x16x32_bf16(ap[1], bfr[1][nt], accp[nt], 0, 0, 0);
            accn[nt] = __builtin_amdgcn_mfma_f32_16x16x32_bf16(an[0], bfr[0][nt], accn[nt], 0, 0, 0);
            accn[nt] = __builtin_amdgcn_mfma_f32_16x16x32_bf16(an[1], bfr[1][nt], accn[nt], 0, 0, 0);
        }
        float dvr[4];
#pragma unroll
        for (int reg = 0; reg < 4; reg++) {
            int node = t * 16 + lg * 4 + reg;
            dvr[reg] = node < n ? rsqrtf((float)cnt[node] + 1.0f) : 0.f;
        }
#pragma unroll
        for (int nt = 0; nt < 4; nt++)
#pragma unroll
            for (int reg = 0; reg < 4; reg++) {
                int node = t * 16 + lg * 4 + reg;
                if (node < n)
                    out[(size_t)node * 64 + nt * 16 + l15] =
                        packfp8(accp[nt][reg] * dvr[reg], accn[nt][reg] * dvr[reg]);
            }
    }
}

// ---- layer-2 GEMM via MFMA, fp8-packed in (unpack->bf16), fp8 out ---------
__global__ __launch_bounds__(256) void gemm2_mfma(
        const ushort* __restrict__ H, const float* __restrict__ W,
        const int* __restrict__ cnt, ushort* __restrict__ out, int n) {
    int lane = threadIdx.x & 63, wid = threadIdx.x >> 6;
    int l15 = lane & 15, lg = lane >> 4;
    bf16x8 bfr[2][4];
#pragma unroll
    for (int kt = 0; kt < 2; kt++)
#pragma unroll
        for (int nt = 0; nt < 4; nt++)
#pragma unroll
            for (int i = 0; i < 8; i++)
                bfr[kt][nt][i] = f2bs(W[(kt * 32 + lg * 8 + i) * 64 + nt * 16 + l15]);
    int ntiles = (n + 15) >> 4;
    for (int t = blockIdx.x * 4 + wid; t < ntiles; t += gridDim.x * 4) {
        int rowA = t * 16 + l15;
        if (rowA >= n) rowA = n - 1;
        const uint4* h = (const uint4*)(H + (size_t)rowA * 64);
        bf16x8 ap[2], an[2];
#pragma unroll
        for (int kt = 0; kt < 2; kt++) {
            uint4 hh = h[kt * 4 + lg];
            uint uu[4] = {hh.x, hh.y, hh.z, hh.w};
#pragma unroll
            for (int j = 0; j < 4; j++) {
                f32x2 lo = unpackfp8(uu[j]);
                f32x2 hi = unpackfp8_hi(uu[j]);
                ap[kt][2 * j]     = f2bs(lo.x); an[kt][2 * j]     = f2bs(lo.y);
                ap[kt][2 * j + 1] = f2bs(hi.x); an[kt][2 * j + 1] = f2bs(hi.y);
            }
        }
        f32x4 accp[4], accn[4];
#pragma unroll
        for (int nt = 0; nt < 4; nt++) { accp[nt] = (f32x4)0.f; accn[nt] = (f32x4)0.f; }
#pragma unroll
        for (int nt = 0; nt < 4; nt++) {
            accp[nt] = __builtin_amdgcn_mfma_f32_16x16x32_bf16(ap[0], bfr[0][nt], accp[nt], 0, 0, 0);
            accp[nt] = __builtin_amdgcn_mfma_f32_16x16x32_bf16(ap[1], bfr[1][nt], accp[nt], 0, 0, 0);
            accn[nt] = __builtin_amdgcn_mfma_f32_16x16x32_bf16(an[0], bfr[0][nt], accn[nt], 0, 0, 0);
            accn[nt] = __builtin_amdgcn_mfma_f32_16x16x32_bf16(an[1], bfr[1][nt], accn[nt], 0, 0, 0);
        }
        float dvr[4];
#pragma unroll
        for (int reg = 0; reg < 4; reg++) {
            int node = t * 16 + lg * 4 + reg;
            dvr[reg] = node < n ? rsqrtf((float)cnt[node] + 1.0f) : 0.f;
        }
#pragma unroll
        for (int nt = 0; nt < 4; nt++)
#pragma unroll
            for (int reg = 0; reg < 4; reg++) {
                int node = t * 16 + lg * 4 + reg;
                if (node < n)
                    out[(size_t)node * 64 + nt * 16 + l15] =
                        packfp8(accp[nt][reg] * dvr[reg], accn[nt][reg] * dvr[reg]);
            }
    }
}

// ---- layer-1 aggregation (conv0): fp8 gather, relu, fp8 out ---------------
__global__ __launch_bounds__(256) void conv_packed(
        const ushort* __restrict__ g, const int* __restrict__ bucket,
        const int* __restrict__ off, const int* __restrict__ cnt,
        const float* __restrict__ bias, ushort* __restrict__ out, int n) {
    int lane = threadIdx.x & 63, wid = threadIdx.x >> 6;
    const uchar* gb = (const uchar*)g;
    uint l2 = (uint)lane * 2;
    float blane = bias[lane];
    int wstart = blockIdx.x * 4 + wid, wstride = gridDim.x * 4;
    for (int v = wstart; v < n; v += wstride) {
        int vu  = __builtin_amdgcn_readfirstlane(v);
        int c   = cnt[vu];
        int ofs = off[vu];
        float dv = rsqrtf((float)c + 1.0f);
        f32x2 acc0 = unpackfp8(*(const ushort*)(gb + ((size_t)(uint)vu << 7) + l2));
        f32x2 acc1 = {0.f, 0.f}, acc2 = {0.f, 0.f}, acc3 = {0.f, 0.f};
        f32x2 acc4 = {0.f, 0.f}, acc5 = {0.f, 0.f}, acc6 = {0.f, 0.f}, acc7 = {0.f, 0.f};
        const int*  bk  = bucket + ofs;
        const int4* bk4 = (const int4*)bk;
        int nq16 = c >> 4;
        for (int q = 0; q < nq16; q++) {
            int4 ra = bk4[4 * q],     rb = bk4[4 * q + 1];
            int4 rc = bk4[4 * q + 2], rd = bk4[4 * q + 3];
            uint u0  = *(const ushort*)(gb + ((size_t)(uint)ra.x << 7) + l2);
            uint u1  = *(const ushort*)(gb + ((size_t)(uint)ra.y << 7) + l2);
            uint u2  = *(const ushort*)(gb + ((size_t)(uint)ra.z << 7) + l2);
            uint u3  = *(const ushort*)(gb + ((size_t)(uint)ra.w << 7) + l2);
            uint u4  = *(const ushort*)(gb + ((size_t)(uint)rb.x << 7) + l2);
            uint u5  = *(const ushort*)(gb + ((size_t)(uint)rb.y << 7) + l2);
            uint u6  = *(const ushort*)(gb + ((size_t)(uint)rb.z << 7) + l2);
            uint u7  = *(const ushort*)(gb + ((size_t)(uint)rb.w << 7) + l2);
            uint u8  = *(const ushort*)(gb + ((size_t)(uint)rc.x << 7) + l2);
            uint u9  = *(const ushort*)(gb + ((size_t)(uint)rc.y << 7) + l2);
            uint u10 = *(const ushort*)(gb + ((size_t)(uint)rc.z << 7) + l2);
            uint u11 = *(const ushort*)(gb + ((size_t)(uint)rc.w << 7) + l2);
            uint u12 = *(const ushort*)(gb + ((size_t)(uint)rd.x << 7) + l2);
            uint u13 = *(const ushort*)(gb + ((size_t)(uint)rd.y << 7) + l2);
            uint u14 = *(const ushort*)(gb + ((size_t)(uint)rd.z << 7) + l2);
            uint u15 = *(const ushort*)(gb + ((size_t)(uint)rd.w << 7) + l2);
            acc0 += unpackfp8(u0);  acc1 += unpackfp8(u1);
            acc2 += unpackfp8(u2);  acc3 += unpackfp8(u3);
            acc4 += unpackfp8(u4);  acc5 += unpackfp8(u5);
            acc6 += unpackfp8(u6);  acc7 += unpackfp8(u7);
            acc0 += unpackfp8(u8);  acc1 += unpackfp8(u9);
            acc2 += unpackfp8(u10); acc3 += unpackfp8(u11);
            acc4 += unpackfp8(u12); acc5 += unpackfp8(u13);
            acc6 += unpackfp8(u14); acc7 += unpackfp8(u15);
        }
        int i = nq16 << 4;
        for (; i + 4 <= c; i += 4) {
            int4 r = *(const int4*)(bk + i);
            acc0 += unpackfp8(*(const ushort*)(gb + ((size_t)(uint)r.x << 7) + l2));
            acc1 += unpackfp8(*(const ushort*)(gb + ((size_t)(uint)r.y << 7) + l2));
            acc2 += unpackfp8(*(const ushort*)(gb + ((size_t)(uint)r.z << 7) + l2));
            acc3 += unpackfp8(*(const ushort*)(gb + ((size_t)(uint)r.w << 7) + l2));
        }
        for (; i < c; i++) {
            int r = bk[i];
            acc0 += unpackfp8(*(const ushort*)(gb + ((size_t)(uint)r << 7) + l2));
        }
        f32x2 acc = ((acc0 + acc1) + (acc2 + acc3)) + ((acc4 + acc5) + (acc6 + acc7));
        float rp = fmaf(dv, acc.x, blane);
        float rn = fmaf(dv, acc.y, blane);
        out[(size_t)vu * 64 + lane] = packfp8(fmaxf(rp, 0.f), fmaxf(rn, 0.f));
    }
}

// ---- weighted colsum of g2 (pos) + last-block summary ---------------------
// colsum[d] = sum_u g2p[u,d]*(w[u]+dis[u]); mean = colsum/N + b2;
// sm = sigmoid(mean); ws = Wdgi@sm; wsv[64] = b2.ws
__global__ __launch_bounds__(256) void colsumw_kernel(
        const ushort* __restrict__ g2, const float* __restrict__ w,
        const int* __restrict__ cnt, const float* __restrict__ b2,
        const float* __restrict__ Wdgi, float* __restrict__ part,
        float* __restrict__ wsv, int* __restrict__ flag, int n, float invN) {
    int lane = threadIdx.x & 63, wid = threadIdx.x >> 6;
    __shared__ float s4[4][64];
    __shared__ int tk;
    float acc = 0.f;
    for (int u = blockIdx.x * 4 + wid; u < n; u += gridDim.x * 4) {
        float wf = w[u] + rsqrtf((float)cnt[u] + 1.0f);
        f32x2 d = unpackfp8(*(const ushort*)(g2 + (size_t)u * 64 + lane));
        acc = fmaf(d.x, wf, acc);
    }
    s4[wid][lane] = acc;
    __syncthreads();
    if (wid == 0)
        part[(size_t)blockIdx.x * 64 + lane] =
            s4[0][lane] + s4[1][lane] + s4[2][lane] + s4[3][lane];
    __threadfence();
    if (threadIdx.x == 0) tk = atomicAdd(flag, 1);
    __syncthreads();
    if (tk == (int)gridDim.x - 1) {
        __threadfence();
        __shared__ float sm[64];
        __shared__ float ws[64];
        float u2 = 0.f;
        for (int g = wid; g < (int)gridDim.x; g += 4)
            u2 += part[(size_t)g * 64 + lane];
        s4[wid][lane] = u2;
        __syncthreads();
        if (wid == 0) {
            u2 = s4[0][lane] + s4[1][lane] + s4[2][lane] + s4[3][lane];
            float mean = fmaf(u2, invN, b2[lane]);
            sm[lane] = 1.f / (1.f + expf(-mean));
        }
        __syncthreads();
        if (threadIdx.x < 64) {
            float a = 0.f;
            for (int j = 0; j < 64; j++) a += Wdgi[threadIdx.x * 64 + j] * sm[j];
            ws[threadIdx.x] = a;
            wsv[threadIdx.x] = a;
        }
        __syncthreads();
        if (threadIdx.x == 0) {
            float b = 0.f;
            for (int j = 0; j < 64; j++) b += b2[j] * ws[j];
            wsv[64] = b;
        }
    }
}

// ---- t2[u] = (g2p[u].ws, g2n[u].ws) — 16-lane group per node --------------
__global__ __launch_bounds__(256) void tdot_kernel(
        const ushort* __restrict__ g2, const float* __restrict__ wsv,
        float2* __restrict__ t2, int n) {
    int lane = threadIdx.x & 63, wid = threadIdx.x >> 6;
    int sub = lane >> 4, dch = lane & 15;
    float w0 = wsv[dch * 4], w1 = wsv[dch * 4 + 1];
    float w2 = wsv[dch * 4 + 2], w3 = wsv[dch * 4 + 3];
    int nq = (n + 3) >> 2;
    for (int qi = blockIdx.x * 4 + wid; qi < nq; qi += gridDim.x * 4) {
        int v = qi * 4 + sub;
        float p = 0.f, q = 0.f;
        if (v < n) {
            uint2 u = *(const uint2*)(g2 + (size_t)v * 64 + dch * 4);
            f32x2 a0 = unpackfp8(u.x), a1 = unpackfp8_hi(u.x);
            f32x2 a2 = unpackfp8(u.y), a3 = unpackfp8_hi(u.y);
            p = a0.x * w0 + a1.x * w1 + a2.x * w2 + a3.x * w3;
            q = a0.y * w0 + a1.y * w1 + a2.y * w2 + a3.y * w3;
        }
        for (int o = 1; o < 16; o <<= 1) {
            p += __shfl_xor(p, o, 64);
            q += __shfl_xor(q, o, 64);
        }
        if (dch == 0 && v < n) t2[v] = make_float2(p, q);
    }
}

// ---- scalar layer-2 conv + loss: thread per node --------------------------
// p = dv*(sum_{r in In(v)} t[r] + t[v]) + b2.ws ; loss terms accumulated
__global__ __launch_bounds__(256) void convloss_kernel(
        const float2* __restrict__ t2, const int* __restrict__ bucket,
        const int* __restrict__ off, const int* __restrict__ cnt,
        const float* __restrict__ wsv, float* __restrict__ lossacc, int n) {
    __shared__ float s[512];
    float b2ws = wsv[64];
    float lp = 0.f, ln = 0.f;
    for (int v = blockIdx.x * 256 + threadIdx.x; v < n; v += gridDim.x * 256) {
        int c   = cnt[v];
        int ofs = off[v];
        float dv = rsqrtf((float)c + 1.0f);
        float2 st = t2[v];
        float sp = st.x, sn = st.y;
        const int* bk = bucket + ofs;
        int i = 0;
        for (; i + 4 <= c; i += 4) {
            int4 r = *(const int4*)(bk + i);
            float2 a0 = t2[r.x], a1 = t2[r.y], a2 = t2[r.z], a3 = t2[r.w];
            sp += (a0.x + a1.x) + (a2.x + a3.x);
            sn += (a0.y + a1.y) + (a2.y + a3.y);
        }
        for (; i < c; i++) {
            float2 a = t2[bk[i]];
            sp += a.x;
            sn += a.y;
        }
        float p = fmaf(dv, sp, b2ws);
        float q = fmaf(dv, sn, b2ws);
        lp += -logf(1.f / (1.f + expf(-p)) + 1e-15f);   // -log(sigmoid(p)+eps)
        ln += -logf(1.f / (1.f + expf( q)) + 1e-15f);   // -log(1-sigmoid(q)+eps)
    }
    s[threadIdx.x] = lp;
    s[256 + threadIdx.x] = ln;
    __syncthreads();
    for (int st2 = 128; st2; st2 >>= 1) {
        if (threadIdx.x < st2) {
            s[threadIdx.x] += s[threadIdx.x + st2];
            s[256 + threadIdx.x] += s[256 + threadIdx.x + st2];
        }
        __syncthreads();
    }
    if (threadIdx.x == 0) atomicAdd(&lossacc[0], s[0]);
    if (threadIdx.x == 1) atomicAdd(&lossacc[1], s[256]);
}

__global__ void finalize_kernel(const float* __restrict__ lossacc,
                                float* __restrict__ out, float invN) {
    out[0] = (lossacc[0] + lossacc[1]) * invN;
}

// ---------------------------------------------------------------------------
extern "C" void kernel_launch(void* const* d_in, const int* in_sizes, int n_in,
                              void* d_out, int out_size, void* d_ws, size_t ws_size,
                              hipStream_t stream) {
    const float* x    = (const float*)d_in[0];
    const float* W1   = (const float*)d_in[1];
    const float* b1   = (const float*)d_in[2];
    const float* W2   = (const float*)d_in[3];
    const float* b2   = (const float*)d_in[4];
    const float* Wdgi = (const float*)d_in[5];
    const int*   edge = (const int*)d_in[6];
    const int*   perm = (const int*)d_in[7];

    const int N = in_sizes[7];
    const int E = in_sizes[6] / 2;
    const int* row = edge;
    const int* col = edge + E;
    const int nb = (N + NPB - 1) >> NB_SHIFT;

    char* wsb = (char*)d_ws;
    size_t woff = 0;
    auto alloc = [&](size_t bytes) -> void* {
        void* p = wsb + woff;
        woff = (woff + bytes + 255) & ~(size_t)255;
        return p;
    };
    int*    bucket   = (int*)   alloc((size_t)nb * BINREGION * 4);  // 9.6 MB
    uint*   bins     = (uint*)  alloc((size_t)nb * BINCAP * 4);     // 8 MB
    int*    bincnt   = (int*)   alloc((size_t)nb * 4);
    int*    cnt      = (int*)   alloc((size_t)N * 4);
    int*    off      = (int*)   alloc((size_t)N * 4);
    float*  w        = (float*) alloc((size_t)N * 4);               // colsum weights
    ushort* G        = (ushort*)alloc((size_t)N * 64 * 2);          // fp8 buffers
    ushort* H        = (ushort*)alloc((size_t)N * 64 * 2);
    float2* t2       = (float2*)alloc((size_t)N * 8);               // per-node (tp,tn)
    float*  part     = (float*) alloc((size_t)CSB * 64 * 4);
    float*  wsv      = (float*) alloc(72 * 4);                      // ws[64] + b2.ws
    float*  lossacc  = (float*) alloc(2 * 4);
    int*    flags    = (int*)   alloc(2 * 4);

    zero_kernel<<<128, 256, 0, stream>>>(w, bincnt, lossacc, flags, nb, N);

    const int nchunks = (E + PCHUNK - 1) / PCHUNK;
    partition_edges<<<nchunks, 256, 0, stream>>>(row, col, bins, bincnt, E, nb);
    place_lds<<<nb, 256, 0, stream>>>(bins, bincnt, bucket, off, cnt, w, N);

    // layer 1: G = fp8((X @ W1) * dis) both branches, aggregate+relu -> H
    gemm1_mfma<<<1024, 256, 0, stream>>>(x, W1, perm, cnt, G, N);
    conv_packed<<<GG, 256, 0, stream>>>(G, bucket, off, cnt, b1, H, N);
    // layer 2: G2 = fp8((H @ W2) * dis) (reuse G)
    gemm2_mfma<<<1024, 256, 0, stream>>>(H, W2, cnt, G, N);

    // summary via weighted colsum (no gather), then ws + b2.ws
    colsumw_kernel<<<CSB, 256, 0, stream>>>(G, w, cnt, b2, Wdgi, part, wsv,
                                            &flags[0], N, 1.0f / N);
    // per-node scalars t = (g2p.ws, g2n.ws)
    tdot_kernel<<<512, 256, 0, stream>>>(G, wsv, t2, N);
    // scalar aggregation + loss (z never materialized)
    convloss_kernel<<<392, 256, 0, stream>>>(t2, bucket, off, cnt, wsv, lossacc, N);
    finalize_kernel<<<1, 1, 0, stream>>>(lossacc, (float*)d_out, 1.0f / N);
}

// Round 22
// 265.525 us; speedup vs baseline: 1.3917x; 1.3917x over previous
//
#include <hip/hip_runtime.h>
#include <hip/hip_bf16.h>
#include <math.h>

#define GG 2048          // conv0 grid
#define NB_SHIFT 9       // 512 nodes per bin
#define NPB 512
#define BINCAP 10240     // edges per bin (mean 8192, 6-sigma ~8740)
#define BINREGION 12288  // padded words per bin bucket region
#define PCHUNK 2048      // edges per partition chunk

typedef __hip_bfloat16 bf16;
typedef unsigned int uint;
typedef unsigned short ushort;
typedef unsigned char uchar;
typedef short bf16x8 __attribute__((ext_vector_type(8)));
typedef float f32x4 __attribute__((ext_vector_type(4)));
typedef float f32x2 __attribute__((ext_vector_type(2)));

__device__ __forceinline__ bf16  f2b(float x) { return __float2bfloat16(x); }
__device__ __forceinline__ short f2bs(float x) {
    bf16 b = __float2bfloat16(x);
    return *reinterpret_cast<short*>(&b);
}
// fp8 e4m3-packed pos/neg: byte0=pos, byte1=neg per dim
__device__ __forceinline__ ushort packfp8(float p, float n) {
    return (ushort)__builtin_amdgcn_cvt_pk_fp8_f32(p, n, 0, false);
}
__device__ __forceinline__ f32x2 unpackfp8(uint u) {
    return __builtin_amdgcn_cvt_pk_f32_fp8((int)u, false);
}
__device__ __forceinline__ f32x2 unpackfp8_hi(uint u) {
    return __builtin_amdgcn_cvt_pk_f32_fp8((int)u, true);
}

// ---- zero: w[N], bincnt, colsum, lossacc ----------------------------------
__global__ __launch_bounds__(256) void zero_kernel(
        float* __restrict__ w, int* __restrict__ bincnt,
        float* __restrict__ colsum, float* __restrict__ lossacc, int nb, int n) {
    int tid = blockIdx.x * 256 + threadIdx.x;
    for (int i = tid; i < n; i += gridDim.x * 256) w[i] = 0.f;
    if (tid < nb) bincnt[tid] = 0;
    if (tid < 64) colsum[tid] = 0.f;
    if (tid < 2)  lossacc[tid] = 0.f;
}

// ---- P1: partition edges into bins of 512 nodes; u = (r<<9)|(c&511) -------
__global__ __launch_bounds__(256) void partition_edges(
        const int* __restrict__ row, const int* __restrict__ col,
        uint* __restrict__ bins, int* __restrict__ bincnt, int E, int nb) {
    __shared__ int lcnt[256];
    __shared__ int lbase[256];
    for (int chunk = blockIdx.x * PCHUNK; chunk < E; chunk += gridDim.x * PCHUNK) {
        int end = chunk + PCHUNK < E ? chunk + PCHUNK : E;
        if (threadIdx.x < nb) lcnt[threadIdx.x] = 0;
        __syncthreads();
        for (int e = chunk + threadIdx.x; e < end; e += 256)
            atomicAdd(&lcnt[col[e] >> NB_SHIFT], 1);
        __syncthreads();
        if (threadIdx.x < nb) {
            lbase[threadIdx.x] = atomicAdd(&bincnt[threadIdx.x], lcnt[threadIdx.x]);
            lcnt[threadIdx.x] = 0;
        }
        __syncthreads();
        for (int e = chunk + threadIdx.x; e < end; e += 256) {
            int c = col[e], r = row[e];
            int g = c >> NB_SHIFT;
            int dst = lbase[g] + atomicAdd(&lcnt[g], 1);
            if (dst < BINCAP)
                bins[(size_t)g * BINCAP + dst] = ((uint)r << NB_SHIFT) | (uint)(c & (NPB - 1));
        }
        __syncthreads();
    }
}

// ---- P2: per bin: LDS hist -> cnt; padded scan -> off; LDS scatter;
// coalesced write-out. Also scatters w[r] += dis[c] (layer-2 colsum weights).
__global__ __launch_bounds__(256) void place_lds(
        const uint* __restrict__ bins, const int* __restrict__ bincnt,
        int* __restrict__ bucket, int* __restrict__ off, int* __restrict__ cnt,
        float* __restrict__ w, int N) {
    __shared__ int lcnt[NPB];
    __shared__ int s[NPB];
    __shared__ int win[BINREGION];
    int b  = blockIdx.x;
    int lo = b << NB_SHIFT;
    int base = b * BINREGION;
    int ne = bincnt[b];
    if (ne > BINCAP) ne = BINCAP;
    const uint* be = bins + (size_t)b * BINCAP;
    for (int i = threadIdx.x; i < NPB; i += 256) lcnt[i] = 0;
    __syncthreads();
    for (int i = threadIdx.x; i < ne; i += 256)
        atomicAdd(&lcnt[be[i] & (NPB - 1)], 1);
    __syncthreads();
    // w scatter: w[row] += rsqrt(deg(col)+1)  (lcnt still holds counts here)
    for (int i = threadIdx.x; i < ne; i += 256) {
        uint u = be[i];
        atomicAdd(&w[(int)(u >> NB_SHIFT)],
                  rsqrtf((float)lcnt[u & (NPB - 1)] + 1.0f));
    }
    int i0 = threadIdx.x, i1 = threadIdx.x + 256;
    s[i0] = (lcnt[i0] + 3) & ~3;
    s[i1] = (lcnt[i1] + 3) & ~3;
    __syncthreads();
    for (int st = 1; st < NPB; st <<= 1) {
        int v0 = i0 >= st ? s[i0 - st] : 0;
        int v1 = i1 >= st ? s[i1 - st] : 0;
        __syncthreads();
        s[i0] += v0; s[i1] += v1;
        __syncthreads();
    }
    for (int i = threadIdx.x; i < NPB; i += 256) {
        int v = lo + i;
        int pc = (lcnt[i] + 3) & ~3;
        int start = s[i] - pc;
        if (v < N) { off[v] = base + start; cnt[v] = lcnt[i]; }
        lcnt[i] = start;
    }
    __syncthreads();
    for (int i = threadIdx.x; i < ne; i += 256) {
        uint u = be[i];
        int slot = atomicAdd(&lcnt[u & (NPB - 1)], 1);
        if (slot < BINREGION) win[slot] = (int)(u >> NB_SHIFT);
    }
    __syncthreads();
    int wsize = s[NPB - 1];
    if (wsize > BINREGION) wsize = BINREGION;
    for (int i = threadIdx.x * 4; i < wsize; i += 1024)
        *(int4*)&bucket[base + i] = *(const int4*)&win[i];
}

// ---- layer-1 GEMM via MFMA; fp8-packed output -----------------------------
__global__ __launch_bounds__(256) void gemm1_mfma(
        const float* __restrict__ X, const float* __restrict__ W,
        const int* __restrict__ perm, const int* __restrict__ cnt,
        ushort* __restrict__ out, int n) {
    int lane = threadIdx.x & 63, wid = threadIdx.x >> 6;
    int l15 = lane & 15, lg = lane >> 4;
    bf16x8 bfr[2][4];
#pragma unroll
    for (int kt = 0; kt < 2; kt++)
#pragma unroll
        for (int nt = 0; nt < 4; nt++)
#pragma unroll
            for (int i = 0; i < 8; i++)
                bfr[kt][nt][i] = f2bs(W[(kt * 32 + lg * 8 + i) * 64 + nt * 16 + l15]);
    int ntiles = (n + 15) >> 4;
    for (int t = blockIdx.x * 4 + wid; t < ntiles; t += gridDim.x * 4) {
        int rowA = t * 16 + l15;
        if (rowA >= n) rowA = n - 1;
        int prow = perm[rowA];
        const float4* xp = (const float4*)(X + (size_t)rowA * 64);
        const float4* xn = (const float4*)(X + (size_t)prow * 64);
        bf16x8 ap[2], an[2];
#pragma unroll
        for (int kt = 0; kt < 2; kt++) {
            float4 p0 = xp[kt * 8 + lg * 2], p1 = xp[kt * 8 + lg * 2 + 1];
            float4 n0 = xn[kt * 8 + lg * 2], n1 = xn[kt * 8 + lg * 2 + 1];
            ap[kt][0] = f2bs(p0.x); ap[kt][1] = f2bs(p0.y);
            ap[kt][2] = f2bs(p0.z); ap[kt][3] = f2bs(p0.w);
            ap[kt][4] = f2bs(p1.x); ap[kt][5] = f2bs(p1.y);
            ap[kt][6] = f2bs(p1.z); ap[kt][7] = f2bs(p1.w);
            an[kt][0] = f2bs(n0.x); an[kt][1] = f2bs(n0.y);
            an[kt][2] = f2bs(n0.z); an[kt][3] = f2bs(n0.w);
            an[kt][4] = f2bs(n1.x); an[kt][5] = f2bs(n1.y);
            an[kt][6] = f2bs(n1.z); an[kt][7] = f2bs(n1.w);
        }
        f32x4 accp[4], accn[4];
#pragma unroll
        for (int nt = 0; nt < 4; nt++) { accp[nt] = (f32x4)0.f; accn[nt] = (f32x4)0.f; }
#pragma unroll
        for (int nt = 0; nt < 4; nt++) {
            accp[nt] = __builtin_amdgcn_mfma_f32_16x16x32_bf16(ap[0], bfr[0][nt], accp[nt], 0, 0, 0);
            accp[nt] = __builtin_amdgcn_mfma_f32_16x16x32_bf16(ap[1], bfr[1][nt], accp[nt], 0, 0, 0);
            accn[nt] = __builtin_amdgcn_mfma_f32_16x16x32_bf16(an[0], bfr[0][nt], accn[nt], 0, 0, 0);
            accn[nt] = __builtin_amdgcn_mfma_f32_16x16x32_bf16(an[1], bfr[1][nt], accn[nt], 0, 0, 0);
        }
        float dvr[4];
#pragma unroll
        for (int reg = 0; reg < 4; reg++) {
            int node = t * 16 + lg * 4 + reg;
            dvr[reg] = node < n ? rsqrtf((float)cnt[node] + 1.0f) : 0.f;
        }
#pragma unroll
        for (int nt = 0; nt < 4; nt++)
#pragma unroll
            for (int reg = 0; reg < 4; reg++) {
                int node = t * 16 + lg * 4 + reg;
                if (node < n)
                    out[(size_t)node * 64 + nt * 16 + l15] =
                        packfp8(accp[nt][reg] * dvr[reg], accn[nt][reg] * dvr[reg]);
            }
    }
}

// ---- layer-2 GEMM via MFMA, fp8-packed in (unpack->bf16), fp8 out ---------
__global__ __launch_bounds__(256) void gemm2_mfma(
        const ushort* __restrict__ H, const float* __restrict__ W,
        const int* __restrict__ cnt, ushort* __restrict__ out, int n) {
    int lane = threadIdx.x & 63, wid = threadIdx.x >> 6;
    int l15 = lane & 15, lg = lane >> 4;
    bf16x8 bfr[2][4];
#pragma unroll
    for (int kt = 0; kt < 2; kt++)
#pragma unroll
        for (int nt = 0; nt < 4; nt++)
#pragma unroll
            for (int i = 0; i < 8; i++)
                bfr[kt][nt][i] = f2bs(W[(kt * 32 + lg * 8 + i) * 64 + nt * 16 + l15]);
    int ntiles = (n + 15) >> 4;
    for (int t = blockIdx.x * 4 + wid; t < ntiles; t += gridDim.x * 4) {
        int rowA = t * 16 + l15;
        if (rowA >= n) rowA = n - 1;
        const uint4* h = (const uint4*)(H + (size_t)rowA * 64);
        bf16x8 ap[2], an[2];
#pragma unroll
        for (int kt = 0; kt < 2; kt++) {
            uint4 hh = h[kt * 4 + lg];
            uint uu[4] = {hh.x, hh.y, hh.z, hh.w};
#pragma unroll
            for (int j = 0; j < 4; j++) {
                f32x2 lo = unpackfp8(uu[j]);
                f32x2 hi = unpackfp8_hi(uu[j]);
                ap[kt][2 * j]     = f2bs(lo.x); an[kt][2 * j]     = f2bs(lo.y);
                ap[kt][2 * j + 1] = f2bs(hi.x); an[kt][2 * j + 1] = f2bs(hi.y);
            }
        }
        f32x4 accp[4], accn[4];
#pragma unroll
        for (int nt = 0; nt < 4; nt++) { accp[nt] = (f32x4)0.f; accn[nt] = (f32x4)0.f; }
#pragma unroll
        for (int nt = 0; nt < 4; nt++) {
            accp[nt] = __builtin_amdgcn_mfma_f32_16x16x32_bf16(ap[0], bfr[0][nt], accp[nt], 0, 0, 0);
            accp[nt] = __builtin_amdgcn_mfma_f32_16x16x32_bf16(ap[1], bfr[1][nt], accp[nt], 0, 0, 0);
            accn[nt] = __builtin_amdgcn_mfma_f32_16x16x32_bf16(an[0], bfr[0][nt], accn[nt], 0, 0, 0);
            accn[nt] = __builtin_amdgcn_mfma_f32_16x16x32_bf16(an[1], bfr[1][nt], accn[nt], 0, 0, 0);
        }
        float dvr[4];
#pragma unroll
        for (int reg = 0; reg < 4; reg++) {
            int node = t * 16 + lg * 4 + reg;
            dvr[reg] = node < n ? rsqrtf((float)cnt[node] + 1.0f) : 0.f;
        }
#pragma unroll
        for (int nt = 0; nt < 4; nt++)
#pragma unroll
            for (int reg = 0; reg < 4; reg++) {
                int node = t * 16 + lg * 4 + reg;
                if (node < n)
                    out[(size_t)node * 64 + nt * 16 + l15] =
                        packfp8(accp[nt][reg] * dvr[reg], accn[nt][reg] * dvr[reg]);
            }
    }
}

// ---- layer-1 aggregation (conv0): fp8 gather, relu, fp8 out ---------------
__global__ __launch_bounds__(256) void conv_packed(
        const ushort* __restrict__ g, const int* __restrict__ bucket,
        const int* __restrict__ off, const int* __restrict__ cnt,
        const float* __restrict__ bias, ushort* __restrict__ out, int n) {
    int lane = threadIdx.x & 63, wid = threadIdx.x >> 6;
    const uchar* gb = (const uchar*)g;
    uint l2 = (uint)lane * 2;
    float blane = bias[lane];
    int wstart = blockIdx.x * 4 + wid, wstride = gridDim.x * 4;
    for (int v = wstart; v < n; v += wstride) {
        int vu  = __builtin_amdgcn_readfirstlane(v);
        int c   = cnt[vu];
        int ofs = off[vu];
        float dv = rsqrtf((float)c + 1.0f);
        f32x2 acc0 = unpackfp8(*(const ushort*)(gb + ((size_t)(uint)vu << 7) + l2));
        f32x2 acc1 = {0.f, 0.f}, acc2 = {0.f, 0.f}, acc3 = {0.f, 0.f};
        f32x2 acc4 = {0.f, 0.f}, acc5 = {0.f, 0.f}, acc6 = {0.f, 0.f}, acc7 = {0.f, 0.f};
        const int*  bk  = bucket + ofs;
        const int4* bk4 = (const int4*)bk;
        int nq16 = c >> 4;
        for (int q = 0; q < nq16; q++) {
            int4 ra = bk4[4 * q],     rb = bk4[4 * q + 1];
            int4 rc = bk4[4 * q + 2], rd = bk4[4 * q + 3];
            uint u0  = *(const ushort*)(gb + ((size_t)(uint)ra.x << 7) + l2);
            uint u1  = *(const ushort*)(gb + ((size_t)(uint)ra.y << 7) + l2);
            uint u2  = *(const ushort*)(gb + ((size_t)(uint)ra.z << 7) + l2);
            uint u3  = *(const ushort*)(gb + ((size_t)(uint)ra.w << 7) + l2);
            uint u4  = *(const ushort*)(gb + ((size_t)(uint)rb.x << 7) + l2);
            uint u5  = *(const ushort*)(gb + ((size_t)(uint)rb.y << 7) + l2);
            uint u6  = *(const ushort*)(gb + ((size_t)(uint)rb.z << 7) + l2);
            uint u7  = *(const ushort*)(gb + ((size_t)(uint)rb.w << 7) + l2);
            uint u8  = *(const ushort*)(gb + ((size_t)(uint)rc.x << 7) + l2);
            uint u9  = *(const ushort*)(gb + ((size_t)(uint)rc.y << 7) + l2);
            uint u10 = *(const ushort*)(gb + ((size_t)(uint)rc.z << 7) + l2);
            uint u11 = *(const ushort*)(gb + ((size_t)(uint)rc.w << 7) + l2);
            uint u12 = *(const ushort*)(gb + ((size_t)(uint)rd.x << 7) + l2);
            uint u13 = *(const ushort*)(gb + ((size_t)(uint)rd.y << 7) + l2);
            uint u14 = *(const ushort*)(gb + ((size_t)(uint)rd.z << 7) + l2);
            uint u15 = *(const ushort*)(gb + ((size_t)(uint)rd.w << 7) + l2);
            acc0 += unpackfp8(u0);  acc1 += unpackfp8(u1);
            acc2 += unpackfp8(u2);  acc3 += unpackfp8(u3);
            acc4 += unpackfp8(u4);  acc5 += unpackfp8(u5);
            acc6 += unpackfp8(u6);  acc7 += unpackfp8(u7);
            acc0 += unpackfp8(u8);  acc1 += unpackfp8(u9);
            acc2 += unpackfp8(u10); acc3 += unpackfp8(u11);
            acc4 += unpackfp8(u12); acc5 += unpackfp8(u13);
            acc6 += unpackfp8(u14); acc7 += unpackfp8(u15);
        }
        int i = nq16 << 4;
        for (; i + 4 <= c; i += 4) {
            int4 r = *(const int4*)(bk + i);
            acc0 += unpackfp8(*(const ushort*)(gb + ((size_t)(uint)r.x << 7) + l2));
            acc1 += unpackfp8(*(const ushort*)(gb + ((size_t)(uint)r.y << 7) + l2));
            acc2 += unpackfp8(*(const ushort*)(gb + ((size_t)(uint)r.z << 7) + l2));
            acc3 += unpackfp8(*(const ushort*)(gb + ((size_t)(uint)r.w << 7) + l2));
        }
        for (; i < c; i++) {
            int r = bk[i];
            acc0 += unpackfp8(*(const ushort*)(gb + ((size_t)(uint)r << 7) + l2));
        }
        f32x2 acc = ((acc0 + acc1) + (acc2 + acc3)) + ((acc4 + acc5) + (acc6 + acc7));
        float rp = fmaf(dv, acc.x, blane);
        float rn = fmaf(dv, acc.y, blane);
        out[(size_t)vu * 64 + lane] = packfp8(fmaxf(rp, 0.f), fmaxf(rn, 0.f));
    }
}

// ---- weighted colsum of g2 (pos): 512 blocks, 4-deep unroll, atomic out ---
__global__ __launch_bounds__(256) void colsumw_part(
        const ushort* __restrict__ g2, const float* __restrict__ w,
        const int* __restrict__ cnt, float* __restrict__ colsum, int n) {
    int lane = threadIdx.x & 63, wid = threadIdx.x >> 6;
    __shared__ float s4[4][64];
    float acc = 0.f;
    int stride = gridDim.x * 4;
    for (int u = blockIdx.x * 4 + wid; u < n; u += 4 * stride) {
        int u1 = u + stride, u2 = u + 2 * stride, u3 = u + 3 * stride;
        float w0 = w[u] + rsqrtf((float)cnt[u] + 1.0f);
        f32x2 d0 = unpackfp8(*(const ushort*)(g2 + (size_t)u * 64 + lane));
        acc = fmaf(d0.x, w0, acc);
        if (u1 < n) {
            float w1 = w[u1] + rsqrtf((float)cnt[u1] + 1.0f);
            f32x2 d1 = unpackfp8(*(const ushort*)(g2 + (size_t)u1 * 64 + lane));
            acc = fmaf(d1.x, w1, acc);
        }
        if (u2 < n) {
            float w2 = w[u2] + rsqrtf((float)cnt[u2] + 1.0f);
            f32x2 d2 = unpackfp8(*(const ushort*)(g2 + (size_t)u2 * 64 + lane));
            acc = fmaf(d2.x, w2, acc);
        }
        if (u3 < n) {
            float w3 = w[u3] + rsqrtf((float)cnt[u3] + 1.0f);
            f32x2 d3 = unpackfp8(*(const ushort*)(g2 + (size_t)u3 * 64 + lane));
            acc = fmaf(d3.x, w3, acc);
        }
    }
    s4[wid][lane] = acc;
    __syncthreads();
    if (wid == 0) {
        float t = s4[0][lane] + s4[1][lane] + s4[2][lane] + s4[3][lane];
        atomicAdd(&colsum[lane], t);
    }
}

// ---- 1-block: sm = sigmoid(colsum/N + b2); ws = Wdgi@sm; wsv[64] = b2.ws --
__global__ void summary_ws(const float* __restrict__ colsum,
                           const float* __restrict__ b2,
                           const float* __restrict__ Wdgi,
                           float* __restrict__ wsv, float invN) {
    __shared__ float sm[64];
    __shared__ float ws[64];
    if (threadIdx.x < 64)
        sm[threadIdx.x] = 1.f / (1.f + expf(-fmaf(colsum[threadIdx.x], invN,
                                                  b2[threadIdx.x])));
    __syncthreads();
    if (threadIdx.x < 64) {
        float a = 0.f;
        for (int j = 0; j < 64; j++) a += Wdgi[threadIdx.x * 64 + j] * sm[j];
        ws[threadIdx.x] = a;
        wsv[threadIdx.x] = a;
    }
    __syncthreads();
    if (threadIdx.x == 0) {
        float b = 0.f;
        for (int j = 0; j < 64; j++) b += b2[j] * ws[j];
        wsv[64] = b;
    }
}

// ---- t2[u] = (g2p[u].ws, g2n[u].ws) — 16-lane group per node --------------
__global__ __launch_bounds__(256) void tdot_kernel(
        const ushort* __restrict__ g2, const float* __restrict__ wsv,
        float2* __restrict__ t2, int n) {
    int lane = threadIdx.x & 63, wid = threadIdx.x >> 6;
    int sub = lane >> 4, dch = lane & 15;
    float w0 = wsv[dch * 4], w1 = wsv[dch * 4 + 1];
    float w2 = wsv[dch * 4 + 2], w3 = wsv[dch * 4 + 3];
    int nq = (n + 3) >> 2;
    for (int qi = blockIdx.x * 4 + wid; qi < nq; qi += gridDim.x * 4) {
        int v = qi * 4 + sub;
        float p = 0.f, q = 0.f;
        if (v < n) {
            uint2 u = *(const uint2*)(g2 + (size_t)v * 64 + dch * 4);
            f32x2 a0 = unpackfp8(u.x), a1 = unpackfp8_hi(u.x);
            f32x2 a2 = unpackfp8(u.y), a3 = unpackfp8_hi(u.y);
            p = a0.x * w0 + a1.x * w1 + a2.x * w2 + a3.x * w3;
            q = a0.y * w0 + a1.y * w1 + a2.y * w2 + a3.y * w3;
        }
        for (int o = 1; o < 16; o <<= 1) {
            p += __shfl_xor(p, o, 64);
            q += __shfl_xor(q, o, 64);
        }
        if (dch == 0 && v < n) t2[v] = make_float2(p, q);
    }
}

// ---- scalar layer-2 conv + loss: thread per node --------------------------
__global__ __launch_bounds__(256) void convloss_kernel(
        const float2* __restrict__ t2, const int* __restrict__ bucket,
        const int* __restrict__ off, const int* __restrict__ cnt,
        const float* __restrict__ wsv, float* __restrict__ lossacc, int n) {
    __shared__ float s[512];
    float b2ws = wsv[64];
    float lp = 0.f, ln = 0.f;
    for (int v = blockIdx.x * 256 + threadIdx.x; v < n; v += gridDim.x * 256) {
        int c   = cnt[v];
        int ofs = off[v];
        float dv = rsqrtf((float)c + 1.0f);
        float2 st = t2[v];
        float sp = st.x, sn = st.y;
        const int* bk = bucket + ofs;
        int i = 0;
        for (; i + 4 <= c; i += 4) {
            int4 r = *(const int4*)(bk + i);
            float2 a0 = t2[r.x], a1 = t2[r.y], a2 = t2[r.z], a3 = t2[r.w];
            sp += (a0.x + a1.x) + (a2.x + a3.x);
            sn += (a0.y + a1.y) + (a2.y + a3.y);
        }
        for (; i < c; i++) {
            float2 a = t2[bk[i]];
            sp += a.x;
            sn += a.y;
        }
        float p = fmaf(dv, sp, b2ws);
        float q = fmaf(dv, sn, b2ws);
        lp += -logf(1.f / (1.f + expf(-p)) + 1e-15f);   // -log(sigmoid(p)+eps)
        ln += -logf(1.f / (1.f + expf( q)) + 1e-15f);   // -log(1-sigmoid(q)+eps)
    }
    s[threadIdx.x] = lp;
    s[256 + threadIdx.x] = ln;
    __syncthreads();
    for (int st2 = 128; st2; st2 >>= 1) {
        if (threadIdx.x < st2) {
            s[threadIdx.x] += s[threadIdx.x + st2];
            s[256 + threadIdx.x] += s[256 + threadIdx.x + st2];
        }
        __syncthreads();
    }
    if (threadIdx.x == 0) atomicAdd(&lossacc[0], s[0]);
    if (threadIdx.x == 1) atomicAdd(&lossacc[1], s[256]);
}

__global__ void finalize_kernel(const float* __restrict__ lossacc,
                                float* __restrict__ out, float invN) {
    out[0] = (lossacc[0] + lossacc[1]) * invN;
}

// ---------------------------------------------------------------------------
extern "C" void kernel_launch(void* const* d_in, const int* in_sizes, int n_in,
                              void* d_out, int out_size, void* d_ws, size_t ws_size,
                              hipStream_t stream) {
    const float* x    = (const float*)d_in[0];
    const float* W1   = (const float*)d_in[1];
    const float* b1   = (const float*)d_in[2];
    const float* W2   = (const float*)d_in[3];
    const float* b2   = (const float*)d_in[4];
    const float* Wdgi = (const float*)d_in[5];
    const int*   edge = (const int*)d_in[6];
    const int*   perm = (const int*)d_in[7];

    const int N = in_sizes[7];
    const int E = in_sizes[6] / 2;
    const int* row = edge;
    const int* col = edge + E;
    const int nb = (N + NPB - 1) >> NB_SHIFT;

    char* wsb = (char*)d_ws;
    size_t woff = 0;
    auto alloc = [&](size_t bytes) -> void* {
        void* p = wsb + woff;
        woff = (woff + bytes + 255) & ~(size_t)255;
        return p;
    };
    int*    bucket   = (int*)   alloc((size_t)nb * BINREGION * 4);  // 9.6 MB
    uint*   bins     = (uint*)  alloc((size_t)nb * BINCAP * 4);     // 8 MB
    int*    bincnt   = (int*)   alloc((size_t)nb * 4);
    int*    cnt      = (int*)   alloc((size_t)N * 4);
    int*    off      = (int*)   alloc((size_t)N * 4);
    float*  w        = (float*) alloc((size_t)N * 4);               // colsum weights
    ushort* G        = (ushort*)alloc((size_t)N * 64 * 2);          // fp8 buffers
    ushort* H        = (ushort*)alloc((size_t)N * 64 * 2);
    float2* t2       = (float2*)alloc((size_t)N * 8);               // per-node (tp,tn)
    float*  colsum   = (float*) alloc(64 * 4);
    float*  wsv      = (float*) alloc(72 * 4);                      // ws[64] + b2.ws
    float*  lossacc  = (float*) alloc(2 * 4);

    zero_kernel<<<128, 256, 0, stream>>>(w, bincnt, colsum, lossacc, nb, N);

    const int nchunks = (E + PCHUNK - 1) / PCHUNK;
    partition_edges<<<nchunks, 256, 0, stream>>>(row, col, bins, bincnt, E, nb);
    place_lds<<<nb, 256, 0, stream>>>(bins, bincnt, bucket, off, cnt, w, N);

    // layer 1: G = fp8((X @ W1) * dis) both branches, aggregate+relu -> H
    gemm1_mfma<<<1024, 256, 0, stream>>>(x, W1, perm, cnt, G, N);
    conv_packed<<<GG, 256, 0, stream>>>(G, bucket, off, cnt, b1, H, N);
    // layer 2: G2 = fp8((H @ W2) * dis) (reuse G)
    gemm2_mfma<<<1024, 256, 0, stream>>>(H, W2, cnt, G, N);

    // summary via weighted colsum (no gather): streaming + atomic merge
    colsumw_part<<<512, 256, 0, stream>>>(G, w, cnt, colsum, N);
    summary_ws<<<1, 256, 0, stream>>>(colsum, b2, Wdgi, wsv, 1.0f / N);
    // per-node scalars t = (g2p.ws, g2n.ws)
    tdot_kernel<<<512, 256, 0, stream>>>(G, wsv, t2, N);
    // scalar aggregation + loss (z never materialized)
    convloss_kernel<<<784, 256, 0, stream>>>(t2, bucket, off, cnt, wsv, lossacc, N);
    finalize_kernel<<<1, 1, 0, stream>>>(lossacc, (float*)d_out, 1.0f / N);
}

// Round 23
// 227.063 us; speedup vs baseline: 1.6274x; 1.1694x over previous
//
#include <hip/hip_runtime.h>
#include <hip/hip_bf16.h>
#include <math.h>

#define GG 2048          // conv grid (colpart rows)
#define RB 32            // colpart rows per stage-A block (GG/RB = 64 blocks)
#define NB_SHIFT 9       // 512 nodes per bin
#define NPB 512
#define BINCAP 10240     // edges per bin (mean 8192, 6-sigma ~8740)
#define BINREGION 12288  // padded words per bin bucket region
#define PCHUNK 2048      // edges per partition chunk

typedef __hip_bfloat16 bf16;
typedef unsigned int uint;
typedef unsigned short ushort;
typedef unsigned char uchar;
typedef short bf16x8 __attribute__((ext_vector_type(8)));
typedef float f32x4 __attribute__((ext_vector_type(4)));
typedef float f32x2 __attribute__((ext_vector_type(2)));

__device__ __forceinline__ bf16  f2b(float x) { return __float2bfloat16(x); }
__device__ __forceinline__ short f2bs(float x) {
    bf16 b = __float2bfloat16(x);
    return *reinterpret_cast<short*>(&b);
}
// fp8 e4m3-packed pos/neg: byte0=pos, byte1=neg per dim
__device__ __forceinline__ ushort packfp8(float p, float n) {
    return (ushort)__builtin_amdgcn_cvt_pk_fp8_f32(p, n, 0, false);
}
__device__ __forceinline__ f32x2 unpackfp8(uint u) {
    return __builtin_amdgcn_cvt_pk_f32_fp8((int)u, false);
}
__device__ __forceinline__ f32x2 unpackfp8_hi(uint u) {
    return __builtin_amdgcn_cvt_pk_f32_fp8((int)u, true);
}

// ---- zero bincnt + lossacc + ticket flag ----------------------------------
__global__ void zero_kernel(int* __restrict__ bincnt, float* __restrict__ lossacc,
                            int* __restrict__ flags, int nb) {
    int i = threadIdx.x;
    if (i < nb) bincnt[i] = 0;
    if (i < 2) { lossacc[i] = 0.f; flags[i] = 0; }
}

// ---- P1: partition edges into bins of 512 nodes; u = (r<<9)|(c&511) -------
__global__ __launch_bounds__(256) void partition_edges(
        const int* __restrict__ row, const int* __restrict__ col,
        uint* __restrict__ bins, int* __restrict__ bincnt, int E, int nb) {
    __shared__ int lcnt[256];
    __shared__ int lbase[256];
    for (int chunk = blockIdx.x * PCHUNK; chunk < E; chunk += gridDim.x * PCHUNK) {
        int end = chunk + PCHUNK < E ? chunk + PCHUNK : E;
        if (threadIdx.x < nb) lcnt[threadIdx.x] = 0;
        __syncthreads();
        for (int e = chunk + threadIdx.x; e < end; e += 256)
            atomicAdd(&lcnt[col[e] >> NB_SHIFT], 1);
        __syncthreads();
        if (threadIdx.x < nb) {
            lbase[threadIdx.x] = atomicAdd(&bincnt[threadIdx.x], lcnt[threadIdx.x]);
            lcnt[threadIdx.x] = 0;
        }
        __syncthreads();
        for (int e = chunk + threadIdx.x; e < end; e += 256) {
            int c = col[e], r = row[e];
            int g = c >> NB_SHIFT;
            int dst = lbase[g] + atomicAdd(&lcnt[g], 1);
            if (dst < BINCAP)
                bins[(size_t)g * BINCAP + dst] = ((uint)r << NB_SHIFT) | (uint)(c & (NPB - 1));
        }
        __syncthreads();
    }
}

// ---- P2: per bin: LDS hist -> cnt; padded scan -> off; LDS scatter;
// coalesced int4 write-out (NO w-scatter: R22 lesson — 1.6M random float
// atomics cost ~90 us of write amplification) --------------------------------
__global__ __launch_bounds__(256) void place_lds(
        const uint* __restrict__ bins, const int* __restrict__ bincnt,
        int* __restrict__ bucket, int* __restrict__ off, int* __restrict__ cnt,
        int N) {
    __shared__ int lcnt[NPB];
    __shared__ int s[NPB];
    __shared__ int win[BINREGION];
    int b  = blockIdx.x;
    int lo = b << NB_SHIFT;
    int base = b * BINREGION;
    int ne = bincnt[b];
    if (ne > BINCAP) ne = BINCAP;
    const uint* be = bins + (size_t)b * BINCAP;
    for (int i = threadIdx.x; i < NPB; i += 256) lcnt[i] = 0;
    __syncthreads();
    for (int i = threadIdx.x; i < ne; i += 256)
        atomicAdd(&lcnt[be[i] & (NPB - 1)], 1);
    __syncthreads();
    int i0 = threadIdx.x, i1 = threadIdx.x + 256;
    s[i0] = (lcnt[i0] + 3) & ~3;
    s[i1] = (lcnt[i1] + 3) & ~3;
    __syncthreads();
    for (int st = 1; st < NPB; st <<= 1) {
        int v0 = i0 >= st ? s[i0 - st] : 0;
        int v1 = i1 >= st ? s[i1 - st] : 0;
        __syncthreads();
        s[i0] += v0; s[i1] += v1;
        __syncthreads();
    }
    for (int i = threadIdx.x; i < NPB; i += 256) {
        int v = lo + i;
        int pc = (lcnt[i] + 3) & ~3;
        int start = s[i] - pc;
        if (v < N) { off[v] = base + start; cnt[v] = lcnt[i]; }
        lcnt[i] = start;
    }
    __syncthreads();
    for (int i = threadIdx.x; i < ne; i += 256) {
        uint u = be[i];
        int slot = atomicAdd(&lcnt[u & (NPB - 1)], 1);
        if (slot < BINREGION) win[slot] = (int)(u >> NB_SHIFT);
    }
    __syncthreads();
    int wsize = s[NPB - 1];
    if (wsize > BINREGION) wsize = BINREGION;
    for (int i = threadIdx.x * 4; i < wsize; i += 1024)
        *(int4*)&bucket[base + i] = *(const int4*)&win[i];
}

// ---- layer-1 GEMM via MFMA; fp8-packed output -----------------------------
__global__ __launch_bounds__(256) void gemm1_mfma(
        const float* __restrict__ X, const float* __restrict__ W,
        const int* __restrict__ perm, const int* __restrict__ cnt,
        ushort* __restrict__ out, int n) {
    int lane = threadIdx.x & 63, wid = threadIdx.x >> 6;
    int l15 = lane & 15, lg = lane >> 4;
    bf16x8 bfr[2][4];
#pragma unroll
    for (int kt = 0; kt < 2; kt++)
#pragma unroll
        for (int nt = 0; nt < 4; nt++)
#pragma unroll
            for (int i = 0; i < 8; i++)
                bfr[kt][nt][i] = f2bs(W[(kt * 32 + lg * 8 + i) * 64 + nt * 16 + l15]);
    int ntiles = (n + 15) >> 4;
    for (int t = blockIdx.x * 4 + wid; t < ntiles; t += gridDim.x * 4) {
        int rowA = t * 16 + l15;
        if (rowA >= n) rowA = n - 1;
        int prow = perm[rowA];
        const float4* xp = (const float4*)(X + (size_t)rowA * 64);
        const float4* xn = (const float4*)(X + (size_t)prow * 64);
        bf16x8 ap[2], an[2];
#pragma unroll
        for (int kt = 0; kt < 2; kt++) {
            float4 p0 = xp[kt * 8 + lg * 2], p1 = xp[kt * 8 + lg * 2 + 1];
            float4 n0 = xn[kt * 8 + lg * 2], n1 = xn[kt * 8 + lg * 2 + 1];
            ap[kt][0] = f2bs(p0.x); ap[kt][1] = f2bs(p0.y);
            ap[kt][2] = f2bs(p0.z); ap[kt][3] = f2bs(p0.w);
            ap[kt][4] = f2bs(p1.x); ap[kt][5] = f2bs(p1.y);
            ap[kt][6] = f2bs(p1.z); ap[kt][7] = f2bs(p1.w);
            an[kt][0] = f2bs(n0.x); an[kt][1] = f2bs(n0.y);
            an[kt][2] = f2bs(n0.z); an[kt][3] = f2bs(n0.w);
            an[kt][4] = f2bs(n1.x); an[kt][5] = f2bs(n1.y);
            an[kt][6] = f2bs(n1.z); an[kt][7] = f2bs(n1.w);
        }
        f32x4 accp[4], accn[4];
#pragma unroll
        for (int nt = 0; nt < 4; nt++) { accp[nt] = (f32x4)0.f; accn[nt] = (f32x4)0.f; }
#pragma unroll
        for (int nt = 0; nt < 4; nt++) {
            accp[nt] = __builtin_amdgcn_mfma_f32_16x16x32_bf16(ap[0], bfr[0][nt], accp[nt], 0, 0, 0);
            accp[nt] = __builtin_amdgcn_mfma_f32_16x16x32_bf16(ap[1], bfr[1][nt], accp[nt], 0, 0, 0);
            accn[nt] = __builtin_amdgcn_mfma_f32_16x16x32_bf16(an[0], bfr[0][nt], accn[nt], 0, 0, 0);
            accn[nt] = __builtin_amdgcn_mfma_f32_16x16x32_bf16(an[1], bfr[1][nt], accn[nt], 0, 0, 0);
        }
        float dvr[4];
#pragma unroll
        for (int reg = 0; reg < 4; reg++) {
            int node = t * 16 + lg * 4 + reg;
            dvr[reg] = node < n ? rsqrtf((float)cnt[node] + 1.0f) : 0.f;
        }
#pragma unroll
        for (int nt = 0; nt < 4; nt++)
#pragma unroll
            for (int reg = 0; reg < 4; reg++) {
                int node = t * 16 + lg * 4 + reg;
                if (node < n)
                    out[(size_t)node * 64 + nt * 16 + l15] =
                        packfp8(accp[nt][reg] * dvr[reg], accn[nt][reg] * dvr[reg]);
            }
    }
}

// ---- layer-2 GEMM via MFMA, fp8-packed in (unpack->bf16), fp8 out ---------
__global__ __launch_bounds__(256) void gemm2_mfma(
        const ushort* __restrict__ H, const float* __restrict__ W,
        const int* __restrict__ cnt, ushort* __restrict__ out, int n) {
    int lane = threadIdx.x & 63, wid = threadIdx.x >> 6;
    int l15 = lane & 15, lg = lane >> 4;
    bf16x8 bfr[2][4];
#pragma unroll
    for (int kt = 0; kt < 2; kt++)
#pragma unroll
        for (int nt = 0; nt < 4; nt++)
#pragma unroll
            for (int i = 0; i < 8; i++)
                bfr[kt][nt][i] = f2bs(W[(kt * 32 + lg * 8 + i) * 64 + nt * 16 + l15]);
    int ntiles = (n + 15) >> 4;
    for (int t = blockIdx.x * 4 + wid; t < ntiles; t += gridDim.x * 4) {
        int rowA = t * 16 + l15;
        if (rowA >= n) rowA = n - 1;
        const uint4* h = (const uint4*)(H + (size_t)rowA * 64);
        bf16x8 ap[2], an[2];
#pragma unroll
        for (int kt = 0; kt < 2; kt++) {
            uint4 hh = h[kt * 4 + lg];
            uint uu[4] = {hh.x, hh.y, hh.z, hh.w};
#pragma unroll
            for (int j = 0; j < 4; j++) {
                f32x2 lo = unpackfp8(uu[j]);
                f32x2 hi = unpackfp8_hi(uu[j]);
                ap[kt][2 * j]     = f2bs(lo.x); an[kt][2 * j]     = f2bs(lo.y);
                ap[kt][2 * j + 1] = f2bs(hi.x); an[kt][2 * j + 1] = f2bs(hi.y);
            }
        }
        f32x4 accp[4], accn[4];
#pragma unroll
        for (int nt = 0; nt < 4; nt++) { accp[nt] = (f32x4)0.f; accn[nt] = (f32x4)0.f; }
#pragma unroll
        for (int nt = 0; nt < 4; nt++) {
            accp[nt] = __builtin_amdgcn_mfma_f32_16x16x32_bf16(ap[0], bfr[0][nt], accp[nt], 0, 0, 0);
            accp[nt] = __builtin_amdgcn_mfma_f32_16x16x32_bf16(ap[1], bfr[1][nt], accp[nt], 0, 0, 0);
            accn[nt] = __builtin_amdgcn_mfma_f32_16x16x32_bf16(an[0], bfr[0][nt], accn[nt], 0, 0, 0);
            accn[nt] = __builtin_amdgcn_mfma_f32_16x16x32_bf16(an[1], bfr[1][nt], accn[nt], 0, 0, 0);
        }
        float dvr[4];
#pragma unroll
        for (int reg = 0; reg < 4; reg++) {
            int node = t * 16 + lg * 4 + reg;
            dvr[reg] = node < n ? rsqrtf((float)cnt[node] + 1.0f) : 0.f;
        }
#pragma unroll
        for (int nt = 0; nt < 4; nt++)
#pragma unroll
            for (int reg = 0; reg < 4; reg++) {
                int node = t * 16 + lg * 4 + reg;
                if (node < n)
                    out[(size_t)node * 64 + nt * 16 + l15] =
                        packfp8(accp[nt][reg] * dvr[reg], accn[nt][reg] * dvr[reg]);
            }
    }
}

// ---- fused GCN aggregation: scalar-pipe addressing + packed f32x2 adds ----
// MODE 0: relu -> out.  MODE 1: raw -> out, pos col-partials -> colpart.
template <int MODE>
__global__ __launch_bounds__(256) void conv_packed(
        const ushort* __restrict__ g, const int* __restrict__ bucket,
        const int* __restrict__ off, const int* __restrict__ cnt,
        const float* __restrict__ bias,
        ushort* __restrict__ out, float* __restrict__ colpart, int n) {
    int lane = threadIdx.x & 63, wid = threadIdx.x >> 6;
    const uchar* gb = (const uchar*)g;
    uint l2 = (uint)lane * 2;
    __shared__ float s[256];
    float colp  = 0.f;
    float blane = bias[lane];
    int wstart = blockIdx.x * 4 + wid, wstride = gridDim.x * 4;
    for (int v = wstart; v < n; v += wstride) {
        int vu  = __builtin_amdgcn_readfirstlane(v);
        int c   = cnt[vu];              // s_load
        int ofs = off[vu];              // s_load
        float dv = rsqrtf((float)c + 1.0f);
        f32x2 acc0 = unpackfp8(*(const ushort*)(gb + ((size_t)(uint)vu << 7) + l2));
        f32x2 acc1 = {0.f, 0.f}, acc2 = {0.f, 0.f}, acc3 = {0.f, 0.f};
        f32x2 acc4 = {0.f, 0.f}, acc5 = {0.f, 0.f}, acc6 = {0.f, 0.f}, acc7 = {0.f, 0.f};
        const int*  bk  = bucket + ofs;            // uniform base
        const int4* bk4 = (const int4*)bk;
        int nq16 = c >> 4;
        for (int q = 0; q < nq16; q++) {           // 16 gathers in flight
            int4 ra = bk4[4 * q],     rb = bk4[4 * q + 1];
            int4 rc = bk4[4 * q + 2], rd = bk4[4 * q + 3];
            uint u0  = *(const ushort*)(gb + ((size_t)(uint)ra.x << 7) + l2);
            uint u1  = *(const ushort*)(gb + ((size_t)(uint)ra.y << 7) + l2);
            uint u2  = *(const ushort*)(gb + ((size_t)(uint)ra.z << 7) + l2);
            uint u3  = *(const ushort*)(gb + ((size_t)(uint)ra.w << 7) + l2);
            uint u4  = *(const ushort*)(gb + ((size_t)(uint)rb.x << 7) + l2);
            uint u5  = *(const ushort*)(gb + ((size_t)(uint)rb.y << 7) + l2);
            uint u6  = *(const ushort*)(gb + ((size_t)(uint)rb.z << 7) + l2);
            uint u7  = *(const ushort*)(gb + ((size_t)(uint)rb.w << 7) + l2);
            uint u8  = *(const ushort*)(gb + ((size_t)(uint)rc.x << 7) + l2);
            uint u9  = *(const ushort*)(gb + ((size_t)(uint)rc.y << 7) + l2);
            uint u10 = *(const ushort*)(gb + ((size_t)(uint)rc.z << 7) + l2);
            uint u11 = *(const ushort*)(gb + ((size_t)(uint)rc.w << 7) + l2);
            uint u12 = *(const ushort*)(gb + ((size_t)(uint)rd.x << 7) + l2);
            uint u13 = *(const ushort*)(gb + ((size_t)(uint)rd.y << 7) + l2);
            uint u14 = *(const ushort*)(gb + ((size_t)(uint)rd.z << 7) + l2);
            uint u15 = *(const ushort*)(gb + ((size_t)(uint)rd.w << 7) + l2);
            acc0 += unpackfp8(u0);  acc1 += unpackfp8(u1);
            acc2 += unpackfp8(u2);  acc3 += unpackfp8(u3);
            acc4 += unpackfp8(u4);  acc5 += unpackfp8(u5);
            acc6 += unpackfp8(u6);  acc7 += unpackfp8(u7);
            acc0 += unpackfp8(u8);  acc1 += unpackfp8(u9);
            acc2 += unpackfp8(u10); acc3 += unpackfp8(u11);
            acc4 += unpackfp8(u12); acc5 += unpackfp8(u13);
            acc6 += unpackfp8(u14); acc7 += unpackfp8(u15);
        }
        int i = nq16 << 4;
        for (; i + 4 <= c; i += 4) {
            int4 r = *(const int4*)(bk + i);
            acc0 += unpackfp8(*(const ushort*)(gb + ((size_t)(uint)r.x << 7) + l2));
            acc1 += unpackfp8(*(const ushort*)(gb + ((size_t)(uint)r.y << 7) + l2));
            acc2 += unpackfp8(*(const ushort*)(gb + ((size_t)(uint)r.z << 7) + l2));
            acc3 += unpackfp8(*(const ushort*)(gb + ((size_t)(uint)r.w << 7) + l2));
        }
        for (; i < c; i++) {
            int r = bk[i];
            acc0 += unpackfp8(*(const ushort*)(gb + ((size_t)(uint)r << 7) + l2));
        }
        f32x2 acc = ((acc0 + acc1) + (acc2 + acc3)) + ((acc4 + acc5) + (acc6 + acc7));
        float rp = fmaf(dv, acc.x, blane);
        float rn = fmaf(dv, acc.y, blane);
        size_t vo = (size_t)vu * 64 + lane;
        if (MODE == 0) {
            out[vo] = packfp8(fmaxf(rp, 0.f), fmaxf(rn, 0.f));
        } else {
            out[vo] = packfp8(rp, rn);
            colp += rp;          // f32 partial (pre-rounding) for summary
        }
    }
    if (MODE == 1) {
        s[wid * 64 + lane] = colp;
        __syncthreads();
        if (wid == 0) {
            float t = s[lane] + s[64 + lane] + s[128 + lane] + s[192 + lane];
            colpart[(size_t)blockIdx.x * 64 + lane] = t;
        }
    }
}

// ---- colreduce + (last block) summary — 64 blocks only, fence is cheap ----
__global__ __launch_bounds__(256) void colreduce_summary(
        const float* __restrict__ colpart, float* __restrict__ colpart2,
        const float* __restrict__ Wdgi, float* __restrict__ wsv,
        int* __restrict__ flag, float invN) {
    int lane = threadIdx.x & 63, w = threadIdx.x >> 6;
    __shared__ float s4[4][64];
    __shared__ int tk;
    float t = 0.f;
    int base = blockIdx.x * RB;
    for (int g = w; g < RB; g += 4) t += colpart[(size_t)(base + g) * 64 + lane];
    s4[w][lane] = t;
    __syncthreads();
    if (w == 0)
        colpart2[(size_t)blockIdx.x * 64 + lane] =
            s4[0][lane] + s4[1][lane] + s4[2][lane] + s4[3][lane];
    __threadfence();
    if (threadIdx.x == 0) tk = atomicAdd(flag, 1);
    __syncthreads();
    if (tk == (int)gridDim.x - 1) {      // last block does the summary
        __threadfence();
        __shared__ float sm[64];
        __shared__ float p4[4][64];
        float u = 0.f;
        for (int g = w; g < (int)gridDim.x; g += 4)
            u += colpart2[(size_t)g * 64 + lane];
        p4[w][lane] = u;
        __syncthreads();
        if (w == 0) {
            u = p4[0][lane] + p4[1][lane] + p4[2][lane] + p4[3][lane];
            sm[lane] = 1.f / (1.f + expf(-u * invN));
        }
        __syncthreads();
        if (threadIdx.x < 64) {
            float a = 0.f;
            for (int j = 0; j < 64; j++) a += Wdgi[threadIdx.x * 64 + j] * sm[j];
            wsv[threadIdx.x] = a;
        }
    }
}

// ---- both losses: plain (no fence/ticket — R19 lesson) ---------------------
__global__ __launch_bounds__(256) void loss4_kernel(
        const ushort* __restrict__ z, const float* __restrict__ wsv,
        float* __restrict__ lossacc, int n) {
    int lane = threadIdx.x & 63, wid = threadIdx.x >> 6;
    int sub = lane >> 4, dch = lane & 15;
    __shared__ float s[16];
    float w0 = wsv[dch * 4], w1 = wsv[dch * 4 + 1];
    float w2 = wsv[dch * 4 + 2], w3 = wsv[dch * 4 + 3];
    float lp = 0.f, ln = 0.f;
    int nq = (n + 3) >> 2;
    for (int qi = blockIdx.x * 4 + wid; qi < nq; qi += gridDim.x * 4) {
        int v = qi * 4 + sub;
        float p = 0.f, q = 0.f;
        if (v < n) {
            uint2 u = *(const uint2*)(z + (size_t)v * 64 + dch * 4);
            f32x2 a0 = unpackfp8(u.x), a1 = unpackfp8_hi(u.x);
            f32x2 a2 = unpackfp8(u.y), a3 = unpackfp8_hi(u.y);
            p = a0.x * w0 + a1.x * w1 + a2.x * w2 + a3.x * w3;
            q = a0.y * w0 + a1.y * w1 + a2.y * w2 + a3.y * w3;
        }
        for (int o = 1; o < 16; o <<= 1) {
            p += __shfl_xor(p, o, 64);
            q += __shfl_xor(q, o, 64);
        }
        if (dch == 0 && v < n) {
            lp += -logf(1.f / (1.f + expf(-p)) + 1e-15f);   // -log(sigmoid(p)+eps)
            ln += -logf(1.f / (1.f + expf( q)) + 1e-15f);   // -log(1-sigmoid(q)+eps)
        }
    }
    lp += __shfl_xor(lp, 16, 64); ln += __shfl_xor(ln, 16, 64);
    lp += __shfl_xor(lp, 32, 64); ln += __shfl_xor(ln, 32, 64);
    if (lane == 0) { s[wid] = lp; s[8 + wid] = ln; }
    __syncthreads();
    if (threadIdx.x == 0) atomicAdd(&lossacc[0], s[0] + s[1] + s[2] + s[3]);
    if (threadIdx.x == 1) atomicAdd(&lossacc[1], s[8] + s[9] + s[10] + s[11]);
}

__global__ void finalize_kernel(const float* __restrict__ lossacc,
                                float* __restrict__ out, float invN) {
    out[0] = (lossacc[0] + lossacc[1]) * invN;
}

// ---------------------------------------------------------------------------
extern "C" void kernel_launch(void* const* d_in, const int* in_sizes, int n_in,
                              void* d_out, int out_size, void* d_ws, size_t ws_size,
                              hipStream_t stream) {
    const float* x    = (const float*)d_in[0];
    const float* W1   = (const float*)d_in[1];
    const float* b1   = (const float*)d_in[2];
    const float* W2   = (const float*)d_in[3];
    const float* b2   = (const float*)d_in[4];
    const float* Wdgi = (const float*)d_in[5];
    const int*   edge = (const int*)d_in[6];
    const int*   perm = (const int*)d_in[7];

    const int N = in_sizes[7];
    const int E = in_sizes[6] / 2;
    const int* row = edge;
    const int* col = edge + E;
    const int nb = (N + NPB - 1) >> NB_SHIFT;

    char* wsb = (char*)d_ws;
    size_t woff = 0;
    auto alloc = [&](size_t bytes) -> void* {
        void* p = wsb + woff;
        woff = (woff + bytes + 255) & ~(size_t)255;
        return p;
    };
    int*    bucket   = (int*)   alloc((size_t)nb * BINREGION * 4);  // 9.6 MB
    uint*   bins     = (uint*)  alloc((size_t)nb * BINCAP * 4);     // 8 MB
    int*    bincnt   = (int*)   alloc((size_t)nb * 4);
    int*    cnt      = (int*)   alloc((size_t)N * 4);
    int*    off      = (int*)   alloc((size_t)N * 4);
    ushort* G        = (ushort*)alloc((size_t)N * 64 * 2);          // fp8 buffers
    ushort* H        = (ushort*)alloc((size_t)N * 64 * 2);
    float*  colpart  = (float*) alloc((size_t)GG * 64 * 4);
    float*  colpart2 = (float*) alloc((size_t)(GG / RB) * 64 * 4);
    float*  wsv      = (float*) alloc(64 * 4);
    float*  lossacc  = (float*) alloc(2 * 4);
    int*    flags    = (int*)   alloc(2 * 4);

    zero_kernel<<<1, 256, 0, stream>>>(bincnt, lossacc, flags, nb);

    const int nchunks = (E + PCHUNK - 1) / PCHUNK;
    partition_edges<<<nchunks, 256, 0, stream>>>(row, col, bins, bincnt, E, nb);
    place_lds<<<nb, 256, 0, stream>>>(bins, bincnt, bucket, off, cnt, N);

    // layer 1: G = fp8((X @ W1) * dis) both branches, aggregate+relu -> H
    gemm1_mfma<<<1024, 256, 0, stream>>>(x, W1, perm, cnt, G, N);
    conv_packed<0><<<GG, 256, 0, stream>>>(G, bucket, off, cnt, b1, H, nullptr, N);
    // layer 2: G = fp8((H @ W2) * dis), aggregate -> z (reuse H) + colpart
    gemm2_mfma<<<1024, 256, 0, stream>>>(H, W2, cnt, G, N);
    conv_packed<1><<<GG, 256, 0, stream>>>(G, bucket, off, cnt, b2, H, colpart, N);

    colreduce_summary<<<GG / RB, 256, 0, stream>>>(colpart, colpart2, Wdgi, wsv,
                                                   &flags[0], 1.0f / N);
    loss4_kernel<<<2048, 256, 0, stream>>>(H, wsv, lossacc, N);
    finalize_kernel<<<1, 1, 0, stream>>>(lossacc, (float*)d_out, 1.0f / N);
}

// Round 24
// 202.195 us; speedup vs baseline: 1.8276x; 1.1230x over previous
//
#include <hip/hip_runtime.h>
#include <hip/hip_bf16.h>
#include <math.h>

#define GG 2048          // conv grid (colpart rows)
#define RB 32            // colpart rows per stage-A block (GG/RB = 64 blocks)
#define NB_SHIFT 9       // 512 nodes per bin
#define NPB 512
#define BINCAP 10240     // edges per bin (mean 8192, 6-sigma ~8740)
#define BINREGION 12288  // padded words per bin bucket region
#define PCHUNK 2048      // edges per partition chunk

typedef __hip_bfloat16 bf16;
typedef unsigned int uint;
typedef unsigned short ushort;
typedef unsigned char uchar;
typedef short bf16x8 __attribute__((ext_vector_type(8)));
typedef float f32x4 __attribute__((ext_vector_type(4)));
typedef float f32x2 __attribute__((ext_vector_type(2)));

__device__ __forceinline__ bf16  f2b(float x) { return __float2bfloat16(x); }
__device__ __forceinline__ short f2bs(float x) {
    bf16 b = __float2bfloat16(x);
    return *reinterpret_cast<short*>(&b);
}
// fp8 e4m3-packed pos/neg: byte0=pos, byte1=neg per dim
__device__ __forceinline__ ushort packfp8(float p, float n) {
    return (ushort)__builtin_amdgcn_cvt_pk_fp8_f32(p, n, 0, false);
}
__device__ __forceinline__ f32x2 unpackfp8(uint u) {
    return __builtin_amdgcn_cvt_pk_f32_fp8((int)u, false);
}
__device__ __forceinline__ f32x2 unpackfp8_hi(uint u) {
    return __builtin_amdgcn_cvt_pk_f32_fp8((int)u, true);
}
// softplus(x) = log(1+e^x) via native exp/log: -log(sigmoid(p)+eps) == softplus(-p)
// (eps=1e-15 only matters at p<-34, unreachable for 64-dim fp8 dots)
__device__ __forceinline__ float softplus(float x) {
    return fmaxf(x, 0.f) + __logf(1.f + __expf(-fabsf(x)));
}

// ---- zero bincnt + lossacc + ticket flag ----------------------------------
__global__ void zero_kernel(int* __restrict__ bincnt, float* __restrict__ lossacc,
                            int* __restrict__ flags, int nb) {
    int i = threadIdx.x;
    if (i < nb) bincnt[i] = 0;
    if (i < 2) { lossacc[i] = 0.f; flags[i] = 0; }
}

// ---- P1: partition edges into bins of 512 nodes; u = (r<<9)|(c&511) -------
__global__ __launch_bounds__(256) void partition_edges(
        const int* __restrict__ row, const int* __restrict__ col,
        uint* __restrict__ bins, int* __restrict__ bincnt, int E, int nb) {
    __shared__ int lcnt[256];
    __shared__ int lbase[256];
    for (int chunk = blockIdx.x * PCHUNK; chunk < E; chunk += gridDim.x * PCHUNK) {
        int end = chunk + PCHUNK < E ? chunk + PCHUNK : E;
        if (threadIdx.x < nb) lcnt[threadIdx.x] = 0;
        __syncthreads();
        for (int e = chunk + threadIdx.x; e < end; e += 256)
            atomicAdd(&lcnt[col[e] >> NB_SHIFT], 1);
        __syncthreads();
        if (threadIdx.x < nb) {
            lbase[threadIdx.x] = atomicAdd(&bincnt[threadIdx.x], lcnt[threadIdx.x]);
            lcnt[threadIdx.x] = 0;
        }
        __syncthreads();
        for (int e = chunk + threadIdx.x; e < end; e += 256) {
            int c = col[e], r = row[e];
            int g = c >> NB_SHIFT;
            int dst = lbase[g] + atomicAdd(&lcnt[g], 1);
            if (dst < BINCAP)
                bins[(size_t)g * BINCAP + dst] = ((uint)r << NB_SHIFT) | (uint)(c & (NPB - 1));
        }
        __syncthreads();
    }
}

// ---- P2: per bin: LDS hist -> cnt; padded scan -> off; LDS scatter;
// coalesced int4 write-out ----------------------------------------------------
__global__ __launch_bounds__(256) void place_lds(
        const uint* __restrict__ bins, const int* __restrict__ bincnt,
        int* __restrict__ bucket, int* __restrict__ off, int* __restrict__ cnt,
        int N) {
    __shared__ int lcnt[NPB];
    __shared__ int s[NPB];
    __shared__ int win[BINREGION];
    int b  = blockIdx.x;
    int lo = b << NB_SHIFT;
    int base = b * BINREGION;
    int ne = bincnt[b];
    if (ne > BINCAP) ne = BINCAP;
    const uint* be = bins + (size_t)b * BINCAP;
    for (int i = threadIdx.x; i < NPB; i += 256) lcnt[i] = 0;
    __syncthreads();
    for (int i = threadIdx.x; i < ne; i += 256)
        atomicAdd(&lcnt[be[i] & (NPB - 1)], 1);
    __syncthreads();
    int i0 = threadIdx.x, i1 = threadIdx.x + 256;
    s[i0] = (lcnt[i0] + 3) & ~3;
    s[i1] = (lcnt[i1] + 3) & ~3;
    __syncthreads();
    for (int st = 1; st < NPB; st <<= 1) {
        int v0 = i0 >= st ? s[i0 - st] : 0;
        int v1 = i1 >= st ? s[i1 - st] : 0;
        __syncthreads();
        s[i0] += v0; s[i1] += v1;
        __syncthreads();
    }
    for (int i = threadIdx.x; i < NPB; i += 256) {
        int v = lo + i;
        int pc = (lcnt[i] + 3) & ~3;
        int start = s[i] - pc;
        if (v < N) { off[v] = base + start; cnt[v] = lcnt[i]; }
        lcnt[i] = start;
    }
    __syncthreads();
    for (int i = threadIdx.x; i < ne; i += 256) {
        uint u = be[i];
        int slot = atomicAdd(&lcnt[u & (NPB - 1)], 1);
        if (slot < BINREGION) win[slot] = (int)(u >> NB_SHIFT);
    }
    __syncthreads();
    int wsize = s[NPB - 1];
    if (wsize > BINREGION) wsize = BINREGION;
    for (int i = threadIdx.x * 4; i < wsize; i += 1024)
        *(int4*)&bucket[base + i] = *(const int4*)&win[i];
}

// ---- layer-1 GEMM via MFMA; fp8-packed output -----------------------------
__global__ __launch_bounds__(256) void gemm1_mfma(
        const float* __restrict__ X, const float* __restrict__ W,
        const int* __restrict__ perm, const int* __restrict__ cnt,
        ushort* __restrict__ out, int n) {
    int lane = threadIdx.x & 63, wid = threadIdx.x >> 6;
    int l15 = lane & 15, lg = lane >> 4;
    bf16x8 bfr[2][4];
#pragma unroll
    for (int kt = 0; kt < 2; kt++)
#pragma unroll
        for (int nt = 0; nt < 4; nt++)
#pragma unroll
            for (int i = 0; i < 8; i++)
                bfr[kt][nt][i] = f2bs(W[(kt * 32 + lg * 8 + i) * 64 + nt * 16 + l15]);
    int ntiles = (n + 15) >> 4;
    for (int t = blockIdx.x * 4 + wid; t < ntiles; t += gridDim.x * 4) {
        int rowA = t * 16 + l15;
        if (rowA >= n) rowA = n - 1;
        int prow = perm[rowA];
        const float4* xp = (const float4*)(X + (size_t)rowA * 64);
        const float4* xn = (const float4*)(X + (size_t)prow * 64);
        bf16x8 ap[2], an[2];
#pragma unroll
        for (int kt = 0; kt < 2; kt++) {
            float4 p0 = xp[kt * 8 + lg * 2], p1 = xp[kt * 8 + lg * 2 + 1];
            float4 n0 = xn[kt * 8 + lg * 2], n1 = xn[kt * 8 + lg * 2 + 1];
            ap[kt][0] = f2bs(p0.x); ap[kt][1] = f2bs(p0.y);
            ap[kt][2] = f2bs(p0.z); ap[kt][3] = f2bs(p0.w);
            ap[kt][4] = f2bs(p1.x); ap[kt][5] = f2bs(p1.y);
            ap[kt][6] = f2bs(p1.z); ap[kt][7] = f2bs(p1.w);
            an[kt][0] = f2bs(n0.x); an[kt][1] = f2bs(n0.y);
            an[kt][2] = f2bs(n0.z); an[kt][3] = f2bs(n0.w);
            an[kt][4] = f2bs(n1.x); an[kt][5] = f2bs(n1.y);
            an[kt][6] = f2bs(n1.z); an[kt][7] = f2bs(n1.w);
        }
        f32x4 accp[4], accn[4];
#pragma unroll
        for (int nt = 0; nt < 4; nt++) { accp[nt] = (f32x4)0.f; accn[nt] = (f32x4)0.f; }
#pragma unroll
        for (int nt = 0; nt < 4; nt++) {
            accp[nt] = __builtin_amdgcn_mfma_f32_16x16x32_bf16(ap[0], bfr[0][nt], accp[nt], 0, 0, 0);
            accp[nt] = __builtin_amdgcn_mfma_f32_16x16x32_bf16(ap[1], bfr[1][nt], accp[nt], 0, 0, 0);
            accn[nt] = __builtin_amdgcn_mfma_f32_16x16x32_bf16(an[0], bfr[0][nt], accn[nt], 0, 0, 0);
            accn[nt] = __builtin_amdgcn_mfma_f32_16x16x32_bf16(an[1], bfr[1][nt], accn[nt], 0, 0, 0);
        }
        float dvr[4];
#pragma unroll
        for (int reg = 0; reg < 4; reg++) {
            int node = t * 16 + lg * 4 + reg;
            dvr[reg] = node < n ? rsqrtf((float)cnt[node] + 1.0f) : 0.f;
        }
#pragma unroll
        for (int nt = 0; nt < 4; nt++)
#pragma unroll
            for (int reg = 0; reg < 4; reg++) {
                int node = t * 16 + lg * 4 + reg;
                if (node < n)
                    out[(size_t)node * 64 + nt * 16 + l15] =
                        packfp8(accp[nt][reg] * dvr[reg], accn[nt][reg] * dvr[reg]);
            }
    }
}

// ---- layer-2 GEMM via MFMA, fp8-packed in (unpack->bf16), fp8 out ---------
__global__ __launch_bounds__(256) void gemm2_mfma(
        const ushort* __restrict__ H, const float* __restrict__ W,
        const int* __restrict__ cnt, ushort* __restrict__ out, int n) {
    int lane = threadIdx.x & 63, wid = threadIdx.x >> 6;
    int l15 = lane & 15, lg = lane >> 4;
    bf16x8 bfr[2][4];
#pragma unroll
    for (int kt = 0; kt < 2; kt++)
#pragma unroll
        for (int nt = 0; nt < 4; nt++)
#pragma unroll
            for (int i = 0; i < 8; i++)
                bfr[kt][nt][i] = f2bs(W[(kt * 32 + lg * 8 + i) * 64 + nt * 16 + l15]);
    int ntiles = (n + 15) >> 4;
    for (int t = blockIdx.x * 4 + wid; t < ntiles; t += gridDim.x * 4) {
        int rowA = t * 16 + l15;
        if (rowA >= n) rowA = n - 1;
        const uint4* h = (const uint4*)(H + (size_t)rowA * 64);
        bf16x8 ap[2], an[2];
#pragma unroll
        for (int kt = 0; kt < 2; kt++) {
            uint4 hh = h[kt * 4 + lg];
            uint uu[4] = {hh.x, hh.y, hh.z, hh.w};
#pragma unroll
            for (int j = 0; j < 4; j++) {
                f32x2 lo = unpackfp8(uu[j]);
                f32x2 hi = unpackfp8_hi(uu[j]);
                ap[kt][2 * j]     = f2bs(lo.x); an[kt][2 * j]     = f2bs(lo.y);
                ap[kt][2 * j + 1] = f2bs(hi.x); an[kt][2 * j + 1] = f2bs(hi.y);
            }
        }
        f32x4 accp[4], accn[4];
#pragma unroll
        for (int nt = 0; nt < 4; nt++) { accp[nt] = (f32x4)0.f; accn[nt] = (f32x4)0.f; }
#pragma unroll
        for (int nt = 0; nt < 4; nt++) {
            accp[nt] = __builtin_amdgcn_mfma_f32_16x16x32_bf16(ap[0], bfr[0][nt], accp[nt], 0, 0, 0);
            accp[nt] = __builtin_amdgcn_mfma_f32_16x16x32_bf16(ap[1], bfr[1][nt], accp[nt], 0, 0, 0);
            accn[nt] = __builtin_amdgcn_mfma_f32_16x16x32_bf16(an[0], bfr[0][nt], accn[nt], 0, 0, 0);
            accn[nt] = __builtin_amdgcn_mfma_f32_16x16x32_bf16(an[1], bfr[1][nt], accn[nt], 0, 0, 0);
        }
        float dvr[4];
#pragma unroll
        for (int reg = 0; reg < 4; reg++) {
            int node = t * 16 + lg * 4 + reg;
            dvr[reg] = node < n ? rsqrtf((float)cnt[node] + 1.0f) : 0.f;
        }
#pragma unroll
        for (int nt = 0; nt < 4; nt++)
#pragma unroll
            for (int reg = 0; reg < 4; reg++) {
                int node = t * 16 + lg * 4 + reg;
                if (node < n)
                    out[(size_t)node * 64 + nt * 16 + l15] =
                        packfp8(accp[nt][reg] * dvr[reg], accn[nt][reg] * dvr[reg]);
            }
    }
}

// ---- fused GCN aggregation: scalar-pipe addressing + packed f32x2 adds ----
// MODE 0: relu -> out.  MODE 1: raw -> out, pos col-partials -> colpart.
template <int MODE>
__global__ __launch_bounds__(256) void conv_packed(
        const ushort* __restrict__ g, const int* __restrict__ bucket,
        const int* __restrict__ off, const int* __restrict__ cnt,
        const float* __restrict__ bias,
        ushort* __restrict__ out, float* __restrict__ colpart, int n) {
    int lane = threadIdx.x & 63, wid = threadIdx.x >> 6;
    const uchar* gb = (const uchar*)g;
    uint l2 = (uint)lane * 2;
    __shared__ float s[256];
    float colp  = 0.f;
    float blane = bias[lane];
    int wstart = blockIdx.x * 4 + wid, wstride = gridDim.x * 4;
    for (int v = wstart; v < n; v += wstride) {
        int vu  = __builtin_amdgcn_readfirstlane(v);
        int c   = cnt[vu];              // s_load
        int ofs = off[vu];              // s_load
        float dv = rsqrtf((float)c + 1.0f);
        f32x2 acc0 = unpackfp8(*(const ushort*)(gb + ((size_t)(uint)vu << 7) + l2));
        f32x2 acc1 = {0.f, 0.f}, acc2 = {0.f, 0.f}, acc3 = {0.f, 0.f};
        f32x2 acc4 = {0.f, 0.f}, acc5 = {0.f, 0.f}, acc6 = {0.f, 0.f}, acc7 = {0.f, 0.f};
        const int*  bk  = bucket + ofs;            // uniform base
        const int4* bk4 = (const int4*)bk;
        int nq16 = c >> 4;
        for (int q = 0; q < nq16; q++) {           // 16 gathers in flight
            int4 ra = bk4[4 * q],     rb = bk4[4 * q + 1];
            int4 rc = bk4[4 * q + 2], rd = bk4[4 * q + 3];
            uint u0  = *(const ushort*)(gb + ((size_t)(uint)ra.x << 7) + l2);
            uint u1  = *(const ushort*)(gb + ((size_t)(uint)ra.y << 7) + l2);
            uint u2  = *(const ushort*)(gb + ((size_t)(uint)ra.z << 7) + l2);
            uint u3  = *(const ushort*)(gb + ((size_t)(uint)ra.w << 7) + l2);
            uint u4  = *(const ushort*)(gb + ((size_t)(uint)rb.x << 7) + l2);
            uint u5  = *(const ushort*)(gb + ((size_t)(uint)rb.y << 7) + l2);
            uint u6  = *(const ushort*)(gb + ((size_t)(uint)rb.z << 7) + l2);
            uint u7  = *(const ushort*)(gb + ((size_t)(uint)rb.w << 7) + l2);
            uint u8  = *(const ushort*)(gb + ((size_t)(uint)rc.x << 7) + l2);
            uint u9  = *(const ushort*)(gb + ((size_t)(uint)rc.y << 7) + l2);
            uint u10 = *(const ushort*)(gb + ((size_t)(uint)rc.z << 7) + l2);
            uint u11 = *(const ushort*)(gb + ((size_t)(uint)rc.w << 7) + l2);
            uint u12 = *(const ushort*)(gb + ((size_t)(uint)rd.x << 7) + l2);
            uint u13 = *(const ushort*)(gb + ((size_t)(uint)rd.y << 7) + l2);
            uint u14 = *(const ushort*)(gb + ((size_t)(uint)rd.z << 7) + l2);
            uint u15 = *(const ushort*)(gb + ((size_t)(uint)rd.w << 7) + l2);
            acc0 += unpackfp8(u0);  acc1 += unpackfp8(u1);
            acc2 += unpackfp8(u2);  acc3 += unpackfp8(u3);
            acc4 += unpackfp8(u4);  acc5 += unpackfp8(u5);
            acc6 += unpackfp8(u6);  acc7 += unpackfp8(u7);
            acc0 += unpackfp8(u8);  acc1 += unpackfp8(u9);
            acc2 += unpackfp8(u10); acc3 += unpackfp8(u11);
            acc4 += unpackfp8(u12); acc5 += unpackfp8(u13);
            acc6 += unpackfp8(u14); acc7 += unpackfp8(u15);
        }
        int i = nq16 << 4;
        for (; i + 4 <= c; i += 4) {
            int4 r = *(const int4*)(bk + i);
            acc0 += unpackfp8(*(const ushort*)(gb + ((size_t)(uint)r.x << 7) + l2));
            acc1 += unpackfp8(*(const ushort*)(gb + ((size_t)(uint)r.y << 7) + l2));
            acc2 += unpackfp8(*(const ushort*)(gb + ((size_t)(uint)r.z << 7) + l2));
            acc3 += unpackfp8(*(const ushort*)(gb + ((size_t)(uint)r.w << 7) + l2));
        }
        for (; i < c; i++) {
            int r = bk[i];
            acc0 += unpackfp8(*(const ushort*)(gb + ((size_t)(uint)r << 7) + l2));
        }
        f32x2 acc = ((acc0 + acc1) + (acc2 + acc3)) + ((acc4 + acc5) + (acc6 + acc7));
        float rp = fmaf(dv, acc.x, blane);
        float rn = fmaf(dv, acc.y, blane);
        size_t vo = (size_t)vu * 64 + lane;
        if (MODE == 0) {
            out[vo] = packfp8(fmaxf(rp, 0.f), fmaxf(rn, 0.f));
        } else {
            out[vo] = packfp8(rp, rn);
            colp += rp;          // f32 partial (pre-rounding) for summary
        }
    }
    if (MODE == 1) {
        s[wid * 64 + lane] = colp;
        __syncthreads();
        if (wid == 0) {
            float t = s[lane] + s[64 + lane] + s[128 + lane] + s[192 + lane];
            colpart[(size_t)blockIdx.x * 64 + lane] = t;
        }
    }
}

// ---- colreduce + (last block) summary — 64 blocks only, fence is cheap ----
__global__ __launch_bounds__(256) void colreduce_summary(
        const float* __restrict__ colpart, float* __restrict__ colpart2,
        const float* __restrict__ Wdgi, float* __restrict__ wsv,
        int* __restrict__ flag, float invN) {
    int lane = threadIdx.x & 63, w = threadIdx.x >> 6;
    __shared__ float s4[4][64];
    __shared__ int tk;
    float t = 0.f;
    int base = blockIdx.x * RB;
    for (int g = w; g < RB; g += 4) t += colpart[(size_t)(base + g) * 64 + lane];
    s4[w][lane] = t;
    __syncthreads();
    if (w == 0)
        colpart2[(size_t)blockIdx.x * 64 + lane] =
            s4[0][lane] + s4[1][lane] + s4[2][lane] + s4[3][lane];
    __threadfence();
    if (threadIdx.x == 0) tk = atomicAdd(flag, 1);
    __syncthreads();
    if (tk == (int)gridDim.x - 1) {      // last block does the summary
        __threadfence();
        __shared__ float sm[64];
        __shared__ float p4[4][64];
        float u = 0.f;
        for (int g = w; g < (int)gridDim.x; g += 4)
            u += colpart2[(size_t)g * 64 + lane];
        p4[w][lane] = u;
        __syncthreads();
        if (w == 0) {
            u = p4[0][lane] + p4[1][lane] + p4[2][lane] + p4[3][lane];
            sm[lane] = 1.f / (1.f + expf(-u * invN));
        }
        __syncthreads();
        if (threadIdx.x < 64) {
            float a = 0.f;
            for (int j = 0; j < 64; j++) a += Wdgi[threadIdx.x * 64 + j] * sm[j];
            wsv[threadIdx.x] = a;
        }
    }
}

// ---- both losses: fast softplus form (R23 lesson: libm logf/expf chains
// at 1/16 lane efficiency were a fixed ~50 us; softplus+native = ~10 instr) --
__global__ __launch_bounds__(256) void loss4_kernel(
        const ushort* __restrict__ z, const float* __restrict__ wsv,
        float* __restrict__ lossacc, int n) {
    int lane = threadIdx.x & 63, wid = threadIdx.x >> 6;
    int sub = lane >> 4, dch = lane & 15;
    __shared__ float s[16];
    float w0 = wsv[dch * 4], w1 = wsv[dch * 4 + 1];
    float w2 = wsv[dch * 4 + 2], w3 = wsv[dch * 4 + 3];
    float lp = 0.f, ln = 0.f;
    int nq = (n + 3) >> 2;
    for (int qi = blockIdx.x * 4 + wid; qi < nq; qi += gridDim.x * 4) {
        int v = qi * 4 + sub;
        float p = 0.f, q = 0.f;
        if (v < n) {
            uint2 u = *(const uint2*)(z + (size_t)v * 64 + dch * 4);
            f32x2 a0 = unpackfp8(u.x), a1 = unpackfp8_hi(u.x);
            f32x2 a2 = unpackfp8(u.y), a3 = unpackfp8_hi(u.y);
            p = a0.x * w0 + a1.x * w1 + a2.x * w2 + a3.x * w3;
            q = a0.y * w0 + a1.y * w1 + a2.y * w2 + a3.y * w3;
        }
        for (int o = 1; o < 16; o <<= 1) {
            p += __shfl_xor(p, o, 64);
            q += __shfl_xor(q, o, 64);
        }
        if (dch == 0 && v < n) {
            lp += softplus(-p);   // == -log(sigmoid(p)+eps)
            ln += softplus(q);    // == -log(1-sigmoid(q)+eps)
        }
    }
    lp += __shfl_xor(lp, 16, 64); ln += __shfl_xor(ln, 16, 64);
    lp += __shfl_xor(lp, 32, 64); ln += __shfl_xor(ln, 32, 64);
    if (lane == 0) { s[wid] = lp; s[8 + wid] = ln; }
    __syncthreads();
    if (threadIdx.x == 0) atomicAdd(&lossacc[0], s[0] + s[1] + s[2] + s[3]);
    if (threadIdx.x == 1) atomicAdd(&lossacc[1], s[8] + s[9] + s[10] + s[11]);
}

__global__ void finalize_kernel(const float* __restrict__ lossacc,
                                float* __restrict__ out, float invN) {
    out[0] = (lossacc[0] + lossacc[1]) * invN;
}

// ---------------------------------------------------------------------------
extern "C" void kernel_launch(void* const* d_in, const int* in_sizes, int n_in,
                              void* d_out, int out_size, void* d_ws, size_t ws_size,
                              hipStream_t stream) {
    const float* x    = (const float*)d_in[0];
    const float* W1   = (const float*)d_in[1];
    const float* b1   = (const float*)d_in[2];
    const float* W2   = (const float*)d_in[3];
    const float* b2   = (const float*)d_in[4];
    const float* Wdgi = (const float*)d_in[5];
    const int*   edge = (const int*)d_in[6];
    const int*   perm = (const int*)d_in[7];

    const int N = in_sizes[7];
    const int E = in_sizes[6] / 2;
    const int* row = edge;
    const int* col = edge + E;
    const int nb = (N + NPB - 1) >> NB_SHIFT;

    char* wsb = (char*)d_ws;
    size_t woff = 0;
    auto alloc = [&](size_t bytes) -> void* {
        void* p = wsb + woff;
        woff = (woff + bytes + 255) & ~(size_t)255;
        return p;
    };
    int*    bucket   = (int*)   alloc((size_t)nb * BINREGION * 4);  // 9.6 MB
    uint*   bins     = (uint*)  alloc((size_t)nb * BINCAP * 4);     // 8 MB
    int*    bincnt   = (int*)   alloc((size_t)nb * 4);
    int*    cnt      = (int*)   alloc((size_t)N * 4);
    int*    off      = (int*)   alloc((size_t)N * 4);
    ushort* G        = (ushort*)alloc((size_t)N * 64 * 2);          // fp8 buffers
    ushort* H        = (ushort*)alloc((size_t)N * 64 * 2);
    float*  colpart  = (float*) alloc((size_t)GG * 64 * 4);
    float*  colpart2 = (float*) alloc((size_t)(GG / RB) * 64 * 4);
    float*  wsv      = (float*) alloc(64 * 4);
    float*  lossacc  = (float*) alloc(2 * 4);
    int*    flags    = (int*)   alloc(2 * 4);

    zero_kernel<<<1, 256, 0, stream>>>(bincnt, lossacc, flags, nb);

    const int nchunks = (E + PCHUNK - 1) / PCHUNK;
    partition_edges<<<nchunks, 256, 0, stream>>>(row, col, bins, bincnt, E, nb);
    place_lds<<<nb, 256, 0, stream>>>(bins, bincnt, bucket, off, cnt, N);

    // layer 1: G = fp8((X @ W1) * dis) both branches, aggregate+relu -> H
    gemm1_mfma<<<1024, 256, 0, stream>>>(x, W1, perm, cnt, G, N);
    conv_packed<0><<<GG, 256, 0, stream>>>(G, bucket, off, cnt, b1, H, nullptr, N);
    // layer 2: G = fp8((H @ W2) * dis), aggregate -> z (reuse H) + colpart
    gemm2_mfma<<<1024, 256, 0, stream>>>(H, W2, cnt, G, N);
    conv_packed<1><<<GG, 256, 0, stream>>>(G, bucket, off, cnt, b2, H, colpart, N);

    colreduce_summary<<<GG / RB, 256, 0, stream>>>(colpart, colpart2, Wdgi, wsv,
                                                   &flags[0], 1.0f / N);
    loss4_kernel<<<1024, 256, 0, stream>>>(H, wsv, lossacc, N);
    finalize_kernel<<<1, 1, 0, stream>>>(lossacc, (float*)d_out, 1.0f / N);
}